// Round 2
// baseline (4723.392 us; speedup 1.0000x reference)
//
#include <hip/hip_runtime.h>
#include <math.h>

#define KK 20
#define NPTS 1024
#define BB 8
#define EPSF 1e-5f

// ============================== KNN =====================================
// One block per (b, n). Distances computed and compared in FP64 so the
// top-20 selection matches the fp64 numpy reference (fp32 distances caused
// boundary flips -> absmax 0.28 in round 1). Lowest-index tie-break.
__global__ __launch_bounds__(256) void knn_kernel(
    const float* __restrict__ x, long bstride, int C,
    int* __restrict__ idx_out)
{
  const int n = blockIdx.x, b = blockIdx.y, t = threadIdx.x;
  extern __shared__ double smd[];
  double* dist = smd;               // NPTS
  double* ctr  = dist + NPTS;       // C
  double* rv   = ctr + C;           // 256
  int*    ri   = (int*)(rv + 256);  // 256
  const float* xb = x + (long)b * bstride;

  for (int c = t; c < C; c += 256) ctr[c] = (double)xb[(long)c * NPTS + n];
  __syncthreads();
  double xnsq = 0.0;
  for (int c = 0; c < C; ++c) xnsq += ctr[c] * ctr[c];
  for (int m = t; m < NPTS; m += 256) {
    double dot = 0.0, msq = 0.0;
    for (int c = 0; c < C; ++c) {
      double xm = (double)xb[(long)c * NPTS + m];
      dot += ctr[c] * xm;
      msq += xm * xm;
    }
    dist[m] = 2.0 * dot - xnsq - msq;   // m==n -> exactly 0, self is top-1
  }
  __syncthreads();
  int* orow = idx_out + ((long)b * NPTS + n) * KK;
  for (int s = 0; s < KK; ++s) {
    double bv = -INFINITY; int bi = NPTS;
    for (int m = t; m < NPTS; m += 256) {
      double v = dist[m];
      if (v > bv) { bv = v; bi = m; }   // ascending scan keeps lowest index on tie
    }
    rv[t] = bv; ri[t] = bi;
    __syncthreads();
    for (int off = 128; off > 0; off >>= 1) {
      if (t < off) {
        double v2 = rv[t + off]; int i2 = ri[t + off];
        if (v2 > rv[t] || (v2 == rv[t] && i2 < ri[t])) { rv[t] = v2; ri[t] = i2; }
      }
      __syncthreads();
    }
    if (t == 0) { orow[s] = ri[0]; dist[ri[0]] = -INFINITY; }
    __syncthreads();
  }
}

// ========================= EdgeConv (2 passes) ==========================
// blockDim == O. One block per (b, n). AccT=double for layers whose output
// feeds a downstream KNN (discrete top-k is sensitive to ~1e-6 feature
// error); AccT=float for layer 4 (feeds only continuous ops).

template <typename AccT>
__global__ __launch_bounds__(256) void ec_stats_kernel(
    const float* __restrict__ x, long bstride, int C,
    const int* __restrict__ idx,
    const float* __restrict__ W, int O,
    double* __restrict__ sums)
{
  const int n = blockIdx.x, b = blockIdx.y, t = threadIdx.x;
  const int C2 = 2 * C;
  extern __shared__ float sm[];
  float* ctr  = sm;                  // C
  float* fvec = ctr + C;             // KK*C2
  float* wt   = fvec + KK * C2;      // O*17
  int*   jj   = (int*)(wt + O * 17); // KK
  const float* xb = x + (long)b * bstride;

  for (int c = t; c < C; c += O) ctr[c] = xb[(long)c * NPTS + n];
  if (t < KK) jj[t] = idx[((long)b * NPTS + n) * KK + t];
  __syncthreads();
  for (int i = t; i < KK * C; i += O) {
    int k = i / C, c = i - k * C;
    float nv = xb[(long)c * NPTS + jj[k]];
    fvec[k * C2 + c]     = nv - ctr[c];
    fvec[k * C2 + C + c] = ctr[c];
  }
  AccT acc[KK];
  #pragma unroll
  for (int k = 0; k < KK; ++k) acc[k] = (AccT)0;
  for (int cb = 0; cb < C2; cb += 16) {
    int cw = min(16, C2 - cb);
    __syncthreads();
    for (int i = t; i < O * cw; i += O) {
      int oo = i / cw, cc = i - oo * cw;
      wt[oo * 17 + cc] = W[(long)oo * C2 + cb + cc];
    }
    __syncthreads();
    for (int c = 0; c < cw; ++c) {
      AccT w = (AccT)wt[t * 17 + c];
      const float* fr = fvec + cb + c;
      #pragma unroll
      for (int k = 0; k < KK; ++k) acc[k] += w * (AccT)fr[k * C2];
    }
  }
  double s = 0.0, sq = 0.0;
  #pragma unroll
  for (int k = 0; k < KK; ++k) { double v = (double)acc[k]; s += v; sq += v * v; }
  atomicAdd(&sums[t], s);
  atomicAdd(&sums[1024 + t], sq);
}

template <typename AccT>
__global__ __launch_bounds__(256) void ec_apply_kernel(
    const float* __restrict__ x, long bstride, int C,
    const int* __restrict__ idx,
    const float* __restrict__ W, int O,
    const double* __restrict__ sums,
    const float* __restrict__ gamma, const float* __restrict__ beta,
    float* __restrict__ xout, long obstride)
{
  const int n = blockIdx.x, b = blockIdx.y, t = threadIdx.x;
  const int C2 = 2 * C;
  extern __shared__ float sm[];
  float* ctr  = sm;
  float* fvec = ctr + C;
  float* wt   = fvec + KK * C2;
  int*   jj   = (int*)(wt + O * 17);
  const float* xb = x + (long)b * bstride;

  for (int c = t; c < C; c += O) ctr[c] = xb[(long)c * NPTS + n];
  if (t < KK) jj[t] = idx[((long)b * NPTS + n) * KK + t];
  __syncthreads();
  for (int i = t; i < KK * C; i += O) {
    int k = i / C, c = i - k * C;
    float nv = xb[(long)c * NPTS + jj[k]];
    fvec[k * C2 + c]     = nv - ctr[c];
    fvec[k * C2 + C + c] = ctr[c];
  }
  AccT acc[KK];
  #pragma unroll
  for (int k = 0; k < KK; ++k) acc[k] = (AccT)0;
  for (int cb = 0; cb < C2; cb += 16) {
    int cw = min(16, C2 - cb);
    __syncthreads();
    for (int i = t; i < O * cw; i += O) {
      int oo = i / cw, cc = i - oo * cw;
      wt[oo * 17 + cc] = W[(long)oo * C2 + cb + cc];
    }
    __syncthreads();
    for (int c = 0; c < cw; ++c) {
      AccT w = (AccT)wt[t * 17 + c];
      const float* fr = fvec + cb + c;
      #pragma unroll
      for (int k = 0; k < KK; ++k) acc[k] += w * (AccT)fr[k * C2];
    }
  }
  const double cnt = (double)BB * NPTS * KK;
  double mean = sums[t] / cnt;
  double var  = sums[1024 + t] / cnt - mean * mean;
  double invd = 1.0 / sqrt(var + (double)EPSF);
  AccT m = (AccT)mean, inv = (AccT)invd;
  AccT gg = (AccT)gamma[t], bt = (AccT)beta[t];
  AccT mx = (AccT)(-INFINITY);
  #pragma unroll
  for (int k = 0; k < KK; ++k) {
    AccT v = (acc[k] - m) * inv * gg + bt;
    v = (v >= (AccT)0) ? v : (AccT)0.2 * v;
    mx = (v > mx) ? v : mx;
  }
  xout[(long)b * obstride + (long)t * NPTS + n] = (float)mx;
}

// ===================== Final 512->1024 conv (2 passes) ==================
#define NT 16
#define CB5 16

__global__ __launch_bounds__(256) void fin_stats_kernel(
    const float* __restrict__ cat, const float* __restrict__ W5,
    double* __restrict__ sums)
{
  const int nt = blockIdx.x, ot = blockIdx.y, b = blockIdx.z, t = threadIdx.x;
  __shared__ float catT[512 * NT];          // 32 KB
  __shared__ float wt[256 * (CB5 + 1)];     // 17 KB
  const float* cbase = cat + (long)b * 512 * NPTS + nt * NT;
  for (int i = t; i < 512 * NT; i += 256) {
    int c = i / NT, nn = i - c * NT;
    catT[i] = cbase[(long)c * NPTS + nn];
  }
  float acc[NT];
  #pragma unroll
  for (int nn = 0; nn < NT; ++nn) acc[nn] = 0.f;
  for (int cb = 0; cb < 512; cb += CB5) {
    __syncthreads();
    for (int i = t; i < 256 * CB5; i += 256) {
      int oo = i / CB5, cc = i - oo * CB5;
      wt[oo * (CB5 + 1) + cc] = W5[(long)(ot * 256 + oo) * 512 + cb + cc];
    }
    __syncthreads();
    for (int c = 0; c < CB5; ++c) {
      float w = wt[t * (CB5 + 1) + c];
      const float* fr = catT + (cb + c) * NT;
      #pragma unroll
      for (int nn = 0; nn < NT; ++nn) acc[nn] += w * fr[nn];
    }
  }
  int o = ot * 256 + t;
  double s = 0.0, sq = 0.0;
  #pragma unroll
  for (int nn = 0; nn < NT; ++nn) { double v = (double)acc[nn]; s += v; sq += v * v; }
  atomicAdd(&sums[o], s);
  atomicAdd(&sums[1024 + o], sq);
}

__device__ inline unsigned fkey(float f) {
  unsigned u = __float_as_uint(f);
  return (u & 0x80000000u) ? ~u : (u | 0x80000000u);
}
__device__ inline float keyf(unsigned k) {
  return __uint_as_float((k & 0x80000000u) ? (k ^ 0x80000000u) : ~k);
}

__global__ __launch_bounds__(256) void fin_apply_kernel(
    const float* __restrict__ cat, const float* __restrict__ W5,
    const double* __restrict__ sums,
    const float* __restrict__ g5, const float* __restrict__ b5,
    unsigned* __restrict__ mkeys)
{
  const int nt = blockIdx.x, ot = blockIdx.y, b = blockIdx.z, t = threadIdx.x;
  __shared__ float catT[512 * NT];
  __shared__ float wt[256 * (CB5 + 1)];
  const float* cbase = cat + (long)b * 512 * NPTS + nt * NT;
  for (int i = t; i < 512 * NT; i += 256) {
    int c = i / NT, nn = i - c * NT;
    catT[i] = cbase[(long)c * NPTS + nn];
  }
  float acc[NT];
  #pragma unroll
  for (int nn = 0; nn < NT; ++nn) acc[nn] = 0.f;
  for (int cb = 0; cb < 512; cb += CB5) {
    __syncthreads();
    for (int i = t; i < 256 * CB5; i += 256) {
      int oo = i / CB5, cc = i - oo * CB5;
      wt[oo * (CB5 + 1) + cc] = W5[(long)(ot * 256 + oo) * 512 + cb + cc];
    }
    __syncthreads();
    for (int c = 0; c < CB5; ++c) {
      float w = wt[t * (CB5 + 1) + c];
      const float* fr = catT + (cb + c) * NT;
      #pragma unroll
      for (int nn = 0; nn < NT; ++nn) acc[nn] += w * fr[nn];
    }
  }
  int o = ot * 256 + t;
  const double cnt = (double)BB * NPTS;
  double mean = sums[o] / cnt;
  double var  = sums[1024 + o] / cnt - mean * mean;
  float inv = (float)(1.0 / sqrt(var + (double)EPSF));
  float m = (float)mean, gg = g5[o], bt = b5[o];
  float mx = -INFINITY;
  #pragma unroll
  for (int nn = 0; nn < NT; ++nn) {
    float v = (acc[nn] - m) * inv * gg + bt;
    v = (v >= 0.f) ? v : 0.2f * v;
    mx = fmaxf(mx, v);
  }
  atomicMax(&mkeys[b * 1024 + o], fkey(mx));
}

__global__ __launch_bounds__(256) void fin_out_kernel(
    const unsigned* __restrict__ mkeys, float* __restrict__ out)
{
  int i = blockIdx.x * 256 + threadIdx.x;
  if (i < BB * 1024) out[i] = keyf(mkeys[i]);
}

// ============================ launch ====================================
extern "C" void kernel_launch(void* const* d_in, const int* in_sizes, int n_in,
                              void* d_out, int out_size, void* d_ws, size_t ws_size,
                              hipStream_t stream)
{
  (void)in_sizes; (void)n_in; (void)out_size; (void)ws_size;
  const float* x0 = (const float*)d_in[0];
  const float* W1 = (const float*)d_in[1];
  const float* g1 = (const float*)d_in[2];
  const float* b1 = (const float*)d_in[3];
  const float* W2 = (const float*)d_in[4];
  const float* g2 = (const float*)d_in[5];
  const float* b2 = (const float*)d_in[6];
  const float* W3 = (const float*)d_in[7];
  const float* g3 = (const float*)d_in[8];
  const float* b3 = (const float*)d_in[9];
  const float* W4 = (const float*)d_in[10];
  const float* g4 = (const float*)d_in[11];
  const float* b4 = (const float*)d_in[12];
  const float* W5 = (const float*)d_in[13];
  const float* g5 = (const float*)d_in[14];
  const float* b5 = (const float*)d_in[15];
  float* outp = (float*)d_out;

  char* w = (char*)d_ws;
  double*   sums   = (double*)w;   w += 2048 * sizeof(double);                // 16 KB
  unsigned* mkeys  = (unsigned*)w; w += (size_t)BB * 1024 * sizeof(unsigned); // 32 KB
  int*      idxbuf = (int*)w;      w += (size_t)BB * NPTS * KK * sizeof(int); // 640 KB
  float*    cat    = (float*)w;    // 8 * 512 * 1024 * 4 = 16 MB

  const long catbs = 512L * NPTS;
  dim3 gbn(NPTS, BB);

  auto run_layer = [&](const float* xin, long bs, int C, const float* Wl, int O,
                       const float* gg, const float* bt, float* xout, bool fp64acc) {
    size_t knn_sm = (size_t)(NPTS + C + 256) * sizeof(double) + 256 * sizeof(int);
    knn_kernel<<<gbn, 256, knn_sm, stream>>>(xin, bs, C, idxbuf);
    hipMemsetAsync(sums, 0, 2048 * sizeof(double), stream);
    size_t ec_sm = (size_t)(C + KK * 2 * C + O * 17) * sizeof(float) + KK * sizeof(int);
    if (fp64acc) {
      ec_stats_kernel<double><<<gbn, O, ec_sm, stream>>>(xin, bs, C, idxbuf, Wl, O, sums);
      ec_apply_kernel<double><<<gbn, O, ec_sm, stream>>>(xin, bs, C, idxbuf, Wl, O, sums,
                                                         gg, bt, xout, catbs);
    } else {
      ec_stats_kernel<float><<<gbn, O, ec_sm, stream>>>(xin, bs, C, idxbuf, Wl, O, sums);
      ec_apply_kernel<float><<<gbn, O, ec_sm, stream>>>(xin, bs, C, idxbuf, Wl, O, sums,
                                                        gg, bt, xout, catbs);
    }
  };

  // layers 1-3 outputs feed later KNNs -> fp64 accumulation; layer 4 -> fp32
  run_layer(x0,               3L * NPTS, 3,   W1, 64,  g1, b1, cat,              true);
  run_layer(cat,              catbs,     64,  W2, 64,  g2, b2, cat + 64 * NPTS,  true);
  run_layer(cat + 64 * NPTS,  catbs,     64,  W3, 128, g3, b3, cat + 128 * NPTS, true);
  run_layer(cat + 128 * NPTS, catbs,     128, W4, 256, g4, b4, cat + 256 * NPTS, false);

  // final 512->1024 conv + BN + lrelu + max over n
  hipMemsetAsync(sums, 0, 2048 * sizeof(double), stream);
  hipMemsetAsync(mkeys, 0, (size_t)BB * 1024 * sizeof(unsigned), stream);
  dim3 gf(NPTS / NT, 4, BB);
  fin_stats_kernel<<<gf, 256, 0, stream>>>(cat, W5, sums);
  fin_apply_kernel<<<gf, 256, 0, stream>>>(cat, W5, sums, g5, b5, mkeys);
  fin_out_kernel<<<(BB * 1024 + 255) / 256, 256, 0, stream>>>(mkeys, outp);
}

// Round 3
// 1529.443 us; speedup vs baseline: 3.0883x; 3.0883x over previous
//
#include <hip/hip_runtime.h>
#include <math.h>

#define KK 20
#define NPTS 1024
#define BB 8
#define EPSF 1e-5f

// ============================== KNN =====================================
// One block per (b, n). FP64 distances + selection (matches fp64 numpy
// reference; fp32 distances flipped a boundary neighbor in round 1).
// Unchanged from round 2 (passing).
__global__ __launch_bounds__(256) void knn_kernel(
    const float* __restrict__ x, long bstride, int C,
    int* __restrict__ idx_out)
{
  const int n = blockIdx.x, b = blockIdx.y, t = threadIdx.x;
  extern __shared__ double smd[];
  double* dist = smd;               // NPTS
  double* ctr  = dist + NPTS;       // C
  double* rv   = ctr + C;           // 256
  int*    ri   = (int*)(rv + 256);  // 256
  const float* xb = x + (long)b * bstride;

  for (int c = t; c < C; c += 256) ctr[c] = (double)xb[(long)c * NPTS + n];
  __syncthreads();
  double xnsq = 0.0;
  for (int c = 0; c < C; ++c) xnsq += ctr[c] * ctr[c];
  for (int m = t; m < NPTS; m += 256) {
    double dot = 0.0, msq = 0.0;
    for (int c = 0; c < C; ++c) {
      double xm = (double)xb[(long)c * NPTS + m];
      dot += ctr[c] * xm;
      msq += xm * xm;
    }
    dist[m] = 2.0 * dot - xnsq - msq;   // m==n -> exactly 0, self is top-1
  }
  __syncthreads();
  int* orow = idx_out + ((long)b * NPTS + n) * KK;
  for (int s = 0; s < KK; ++s) {
    double bv = -INFINITY; int bi = NPTS;
    for (int m = t; m < NPTS; m += 256) {
      double v = dist[m];
      if (v > bv) { bv = v; bi = m; }
    }
    rv[t] = bv; ri[t] = bi;
    __syncthreads();
    for (int off = 128; off > 0; off >>= 1) {
      if (t < off) {
        double v2 = rv[t + off]; int i2 = ri[t + off];
        if (v2 > rv[t] || (v2 == rv[t] && i2 < ri[t])) { rv[t] = v2; ri[t] = i2; }
      }
      __syncthreads();
    }
    if (t == 0) { orow[s] = ri[0]; dist[ri[0]] = -INFINITY; }
    __syncthreads();
  }
}

// ==================== Fused EdgeConv (single pass) ======================
// y[o][n][k] = sum_c w1[o][c]*x[c][j_k] + sum_c (w2-w1)[o][c]*x[c][n]
// One pass computes: raw max over k (monotone norm+lrelu commutes with max
// since gamma>0, inv>0), and sum/sumsq over k for BN stats.
// Block: 256 thr = 4 waves; wave = one point; lane owns RO=O/64 channels.
template <typename AccT, int C, int O, int RO, int CB>
__global__ __launch_bounds__(256) void ec_fused(
    const float* __restrict__ x, long bstride,
    const int* __restrict__ idx,
    const float* __restrict__ W,
    double* __restrict__ sums,
    AccT* __restrict__ yraw)          // [b][n][O] raw max over k
{
  const int t = threadIdx.x, b = blockIdx.y;
  const int p = t >> 6, lane = t & 63;
  const int n0 = blockIdx.x * 4;
  const int n = n0 + p;
  const int obase = lane * RO;
  const int OP = O + 4, CBP = CB + 1;
  const float* xb = x + (long)b * bstride;

  extern __shared__ char smraw[];
  float* s_w1  = (float*)smraw;               // [CB][OP]
  float* s_wd  = s_w1 + CB * OP;              // [CB][OP]  (w2 - w1)
  float* s_xg  = s_wd + CB * OP;              // [4][KK][CBP] gathered nbr x
  float* s_ctr = s_xg + 4 * KK * CBP;         // [4][CB]
  int*   s_jj  = (int*)(s_ctr + 4 * CB);      // [4][KK]
  AccT*  red   = (AccT*)smraw;                // epilogue alias: [2][4][O]

  if (t < 4 * KK) {
    int pp = t / KK, k = t - pp * KK;
    s_jj[t] = idx[((long)b * NPTS + (n0 + pp)) * KK + k];
  }

  AccT kacc[RO][KK];
  AccT cacc[RO];
  #pragma unroll
  for (int r = 0; r < RO; ++r) {
    cacc[r] = (AccT)0;
    #pragma unroll
    for (int k = 0; k < KK; ++k) kacc[r][k] = (AccT)0;
  }

  for (int c0 = 0; c0 < C; c0 += CB) {
    __syncthreads();
    // stage weights (w1 and w2-w1), chunk [c0, c0+CB)
    for (int i = t; i < CB * O; i += 256) {
      int o = i / CB, cc = i - o * CB;
      float a  = W[(long)o * (2 * C) + c0 + cc];
      float b2 = W[(long)o * (2 * C) + C + c0 + cc];
      s_w1[cc * OP + o] = a;
      s_wd[cc * OP + o] = b2 - a;
    }
    // stage centers
    for (int i = t; i < 4 * CB; i += 256) {
      int pp = i / CB, cc = i - pp * CB;
      s_ctr[pp * CB + cc] = xb[(long)(c0 + cc) * NPTS + n0 + pp];
    }
    // stage gathered neighbors (raw, no subtraction)
    for (int i = t; i < 4 * KK * CB; i += 256) {
      int k = i % KK; int rest = i / KK;
      int cc = rest % CB; int pp = rest / CB;
      s_xg[(pp * KK + k) * CBP + cc] = xb[(long)(c0 + cc) * NPTS + s_jj[pp * KK + k]];
    }
    __syncthreads();
    for (int cc = 0; cc < CB; ++cc) {
      float wv[RO], wdv[RO];
      if constexpr (RO == 4) {
        float4 a = *(const float4*)&s_w1[cc * OP + obase];
        float4 d = *(const float4*)&s_wd[cc * OP + obase];
        wv[0]=a.x; wv[1]=a.y; wv[2]=a.z; wv[3]=a.w;
        wdv[0]=d.x; wdv[1]=d.y; wdv[2]=d.z; wdv[3]=d.w;
      } else if constexpr (RO == 2) {
        float2 a = *(const float2*)&s_w1[cc * OP + obase];
        float2 d = *(const float2*)&s_wd[cc * OP + obase];
        wv[0]=a.x; wv[1]=a.y; wdv[0]=d.x; wdv[1]=d.y;
      } else {
        wv[0] = s_w1[cc * OP + obase];
        wdv[0] = s_wd[cc * OP + obase];
      }
      float cv = s_ctr[p * CB + cc];
      #pragma unroll
      for (int r = 0; r < RO; ++r) cacc[r] += (AccT)wdv[r] * (AccT)cv;
      #pragma unroll
      for (int k = 0; k < KK; ++k) {
        float fv = s_xg[(p * KK + k) * CBP + cc];
        #pragma unroll
        for (int r = 0; r < RO; ++r) kacc[r][k] += (AccT)wv[r] * (AccT)fv;
      }
    }
  }

  // epilogue: per-thread max over k + stats partials
  AccT psum[RO], psq[RO], pmx[RO];
  #pragma unroll
  for (int r = 0; r < RO; ++r) { psum[r] = (AccT)0; psq[r] = (AccT)0; pmx[r] = (AccT)(-INFINITY); }
  #pragma unroll
  for (int k = 0; k < KK; ++k) {
    #pragma unroll
    for (int r = 0; r < RO; ++r) {
      AccT y = kacc[r][k] + cacc[r];
      psum[r] += y; psq[r] += y * y;
      pmx[r] = (y > pmx[r]) ? y : pmx[r];
    }
  }
  // raw k-max, coalesced: yraw[b][n][o]
  #pragma unroll
  for (int r = 0; r < RO; ++r)
    yraw[((long)b * NPTS + n) * O + obase + r] = pmx[r];

  __syncthreads();   // all LDS compute reads done; alias as reduction space
  #pragma unroll
  for (int r = 0; r < RO; ++r) {
    red[p * O + obase + r] = psum[r];
    red[4 * O + p * O + obase + r] = psq[r];
  }
  __syncthreads();
  if (t < O) {
    double s = 0.0, q = 0.0;
    #pragma unroll
    for (int w = 0; w < 4; ++w) {
      s += (double)red[w * O + t];
      q += (double)red[4 * O + w * O + t];
    }
    atomicAdd(&sums[t], s);
    atomicAdd(&sums[1024 + t], q);
  }
}

// normalize + lrelu the raw k-max, write into cat layout [b][o][n]
template <typename AccT, int O, int OL>
__global__ __launch_bounds__(256) void ec_norm(
    const AccT* __restrict__ yraw, const double* __restrict__ sums,
    const float* __restrict__ gamma, const float* __restrict__ beta,
    float* __restrict__ xout)
{
  int i = blockIdx.x * 256 + threadIdx.x;
  int n = i & (NPTS - 1);
  int o = (i >> 10) & (O - 1);
  int b = i >> (10 + OL);
  const double cnt = (double)BB * NPTS * KK;
  double m = sums[o] / cnt;
  double var = sums[1024 + o] / cnt - m * m;
  double inv = 1.0 / sqrt(var + (double)EPSF);
  AccT y = yraw[((long)b * NPTS + n) * O + o];
  AccT v = (y - (AccT)m) * (AccT)inv * (AccT)gamma[o] + (AccT)beta[o];
  v = (v >= (AccT)0) ? v : (AccT)0.2 * v;
  xout[(long)b * (512L * NPTS) + (long)o * NPTS + n] = (float)v;
}

// ============== Final 512->1024 conv, fused single pass =================
__device__ inline unsigned fkey(float f) {
  unsigned u = __float_as_uint(f);
  return (u & 0x80000000u) ? ~u : (u | 0x80000000u);
}
__device__ inline float keyf(unsigned k) {
  return __uint_as_float((k & 0x80000000u) ? (k ^ 0x80000000u) : ~k);
}

__global__ __launch_bounds__(256) void fin_fused(
    const float* __restrict__ cat, const float* __restrict__ W5,
    double* __restrict__ sums, unsigned* __restrict__ mkeys)
{
  const int nt = blockIdx.x, ot = blockIdx.y, t = threadIdx.x;
  const int w = t >> 6, lane = t & 63;
  const int col0 = nt * 16;             // 16 columns (same b)
  const int b = col0 >> 10;
  const int nb = col0 & 1023;
  const int obase = lane * 4;           // within 256-o tile

  __shared__ float sm[32 * 260 + 32 * 16];
  float* s_w = sm;                      // [cc][260]
  float* s_f = sm + 32 * 260;           // [cc][16]

  float acc[4][4];
  #pragma unroll
  for (int r = 0; r < 4; ++r)
    #pragma unroll
    for (int j = 0; j < 4; ++j) acc[r][j] = 0.f;

  for (int c0 = 0; c0 < 512; c0 += 32) {
    __syncthreads();
    for (int i = t; i < 32 * 256; i += 256) {
      int o = i >> 5, cc = i & 31;
      s_w[cc * 260 + o] = W5[(long)(ot * 256 + o) * 512 + c0 + cc];
    }
    for (int i = t; i < 32 * 16; i += 256) {
      int cc = i >> 4, nn = i & 15;
      s_f[cc * 16 + nn] = cat[((long)b * 512 + c0 + cc) * 1024 + nb + nn];
    }
    __syncthreads();
    #pragma unroll 8
    for (int cc = 0; cc < 32; ++cc) {
      float4 wq = *(const float4*)&s_w[cc * 260 + obase];
      float4 fq = *(const float4*)&s_f[cc * 16 + w * 4];
      float wv[4] = {wq.x, wq.y, wq.z, wq.w};
      float fv[4] = {fq.x, fq.y, fq.z, fq.w};
      #pragma unroll
      for (int r = 0; r < 4; ++r)
        #pragma unroll
        for (int j = 0; j < 4; ++j) acc[r][j] += wv[r] * fv[j];
    }
  }

  float psum[4], psq[4], pmx[4];
  #pragma unroll
  for (int r = 0; r < 4; ++r) {
    psum[r] = 0.f; psq[r] = 0.f; pmx[r] = -INFINITY;
    #pragma unroll
    for (int j = 0; j < 4; ++j) {
      float v = acc[r][j];
      psum[r] += v; psq[r] += v * v; pmx[r] = fmaxf(pmx[r], v);
    }
  }
  __syncthreads();
  float* red_s = sm;            // [4][256]
  float* red_q = sm + 1024;     // [4][256]
  float* red_m = sm + 2048;     // [4][256]
  #pragma unroll
  for (int r = 0; r < 4; ++r) {
    red_s[w * 256 + obase + r] = psum[r];
    red_q[w * 256 + obase + r] = psq[r];
    red_m[w * 256 + obase + r] = pmx[r];
  }
  __syncthreads();
  if (t < 256) {
    float s = 0.f, q = 0.f, m = -INFINITY;
    #pragma unroll
    for (int ww = 0; ww < 4; ++ww) {
      s += red_s[ww * 256 + t];
      q += red_q[ww * 256 + t];
      m = fmaxf(m, red_m[ww * 256 + t]);
    }
    int o = ot * 256 + t;
    atomicAdd(&sums[o], (double)s);
    atomicAdd(&sums[1024 + o], (double)q);
    atomicMax(&mkeys[b * 1024 + o], fkey(m));
  }
}

__global__ __launch_bounds__(256) void fin_norm(
    const unsigned* __restrict__ mkeys, const double* __restrict__ sums,
    const float* __restrict__ g, const float* __restrict__ bt,
    float* __restrict__ out)
{
  int i = blockIdx.x * 256 + threadIdx.x;   // 8192
  int o = i & 1023;
  double m = sums[o] / 8192.0;
  double var = sums[1024 + o] / 8192.0 - m * m;
  float inv = (float)(1.0 / sqrt(var + (double)EPSF));
  float y = keyf(mkeys[i]);
  float v = (y - (float)m) * inv * g[o] + bt[o];
  out[i] = (v >= 0.f) ? v : 0.2f * v;
}

// ============================ launch ====================================
static size_t ec_lds_bytes(int C, int O, int CB, size_t accsz) {
  size_t stage = (size_t)CB * (O + 4) * 4 * 2 + (size_t)4 * KK * (CB + 1) * 4
               + (size_t)4 * CB * 4 + (size_t)4 * KK * 4;
  size_t red = (size_t)8 * O * accsz;
  return stage > red ? stage : red;
}

extern "C" void kernel_launch(void* const* d_in, const int* in_sizes, int n_in,
                              void* d_out, int out_size, void* d_ws, size_t ws_size,
                              hipStream_t stream)
{
  (void)in_sizes; (void)n_in; (void)out_size; (void)ws_size;
  const float* x0 = (const float*)d_in[0];
  const float* W1 = (const float*)d_in[1];
  const float* g1 = (const float*)d_in[2];
  const float* b1 = (const float*)d_in[3];
  const float* W2 = (const float*)d_in[4];
  const float* g2 = (const float*)d_in[5];
  const float* b2 = (const float*)d_in[6];
  const float* W3 = (const float*)d_in[7];
  const float* g3 = (const float*)d_in[8];
  const float* b3 = (const float*)d_in[9];
  const float* W4 = (const float*)d_in[10];
  const float* g4 = (const float*)d_in[11];
  const float* b4 = (const float*)d_in[12];
  const float* W5 = (const float*)d_in[13];
  const float* g5 = (const float*)d_in[14];
  const float* b5 = (const float*)d_in[15];
  float* outp = (float*)d_out;

  char* w = (char*)d_ws;
  double*   sums   = (double*)w;   w += 2048 * sizeof(double);                // 16 KB
  unsigned* mkeys  = (unsigned*)w; w += (size_t)BB * 1024 * sizeof(unsigned); // 32 KB
  int*      idxbuf = (int*)w;      w += (size_t)BB * NPTS * KK * sizeof(int); // 640 KB
  char*     yraw   = w;            w += (size_t)BB * NPTS * 128 * sizeof(double); // 8 MB (max)
  float*    cat    = (float*)w;    // 8 * 512 * 1024 * 4 = 16 MB

  const long catbs = 512L * NPTS;
  dim3 gknn(NPTS, BB);
  dim3 gec(NPTS / 4, BB);

  // ---- layer 1: x0 (C=3) -> cat[0:64), fp64 acc ----
  {
    size_t ksm = (size_t)(NPTS + 3 + 256) * sizeof(double) + 256 * sizeof(int);
    knn_kernel<<<gknn, 256, ksm, stream>>>(x0, 3L * NPTS, 3, idxbuf);
    hipMemsetAsync(sums, 0, 2048 * sizeof(double), stream);
    ec_fused<double, 3, 64, 1, 3><<<gec, 256, ec_lds_bytes(3, 64, 3, 8), stream>>>(
        x0, 3L * NPTS, idxbuf, W1, sums, (double*)yraw);
    ec_norm<double, 64, 6><<<BB * 64 * NPTS / 256, 256, 0, stream>>>(
        (const double*)yraw, sums, g1, b1, cat);
  }
  // ---- layer 2: cat[0:64) -> cat[64:128), fp64 acc ----
  {
    size_t ksm = (size_t)(NPTS + 64 + 256) * sizeof(double) + 256 * sizeof(int);
    knn_kernel<<<gknn, 256, ksm, stream>>>(cat, catbs, 64, idxbuf);
    hipMemsetAsync(sums, 0, 2048 * sizeof(double), stream);
    ec_fused<double, 64, 64, 1, 16><<<gec, 256, ec_lds_bytes(64, 64, 16, 8), stream>>>(
        cat, catbs, idxbuf, W2, sums, (double*)yraw);
    ec_norm<double, 64, 6><<<BB * 64 * NPTS / 256, 256, 0, stream>>>(
        (const double*)yraw, sums, g2, b2, cat + 64 * NPTS);
  }
  // ---- layer 3: cat[64:128) -> cat[128:256), fp64 acc ----
  {
    size_t ksm = (size_t)(NPTS + 64 + 256) * sizeof(double) + 256 * sizeof(int);
    knn_kernel<<<gknn, 256, ksm, stream>>>(cat + 64 * NPTS, catbs, 64, idxbuf);
    hipMemsetAsync(sums, 0, 2048 * sizeof(double), stream);
    ec_fused<double, 64, 128, 2, 16><<<gec, 256, ec_lds_bytes(64, 128, 16, 8), stream>>>(
        cat + 64 * NPTS, catbs, idxbuf, W3, sums, (double*)yraw);
    ec_norm<double, 128, 7><<<BB * 128 * NPTS / 256, 256, 0, stream>>>(
        (const double*)yraw, sums, g3, b3, cat + 128 * NPTS);
  }
  // ---- layer 4: cat[128:256) -> cat[256:512), fp32 acc (continuous path) ----
  {
    size_t ksm = (size_t)(NPTS + 128 + 256) * sizeof(double) + 256 * sizeof(int);
    knn_kernel<<<gknn, 256, ksm, stream>>>(cat + 128 * NPTS, catbs, 128, idxbuf);
    hipMemsetAsync(sums, 0, 2048 * sizeof(double), stream);
    ec_fused<float, 128, 256, 4, 16><<<gec, 256, ec_lds_bytes(128, 256, 16, 4), stream>>>(
        cat + 128 * NPTS, catbs, idxbuf, W4, sums, (float*)yraw);
    ec_norm<float, 256, 8><<<BB * 256 * NPTS / 256, 256, 0, stream>>>(
        (const float*)yraw, sums, g4, b4, cat + 256 * NPTS);
  }

  // ---- final 512->1024 conv + BN + lrelu + max over n (single pass) ----
  hipMemsetAsync(sums, 0, 2048 * sizeof(double), stream);
  hipMemsetAsync(mkeys, 0, (size_t)BB * 1024 * sizeof(unsigned), stream);
  dim3 gf(512, 4);
  fin_fused<<<gf, 256, 0, stream>>>(cat, W5, sums, mkeys);
  fin_norm<<<BB * 1024 / 256, 256, 0, stream>>>(mkeys, sums, g5, b5, outp);
}

// Round 4
// 1258.115 us; speedup vs baseline: 3.7543x; 1.2157x over previous
//
#include <hip/hip_runtime.h>
#include <math.h>

#define KK 20
#define NPTS 1024
#define BB 8
#define EPSF 1e-5f

// ====================== KNN v2: wave-per-point ==========================
// xx[b][m] = sum_c x[c][m]^2, fp64, fma-chained in ascending c so the dot
// accumulation in knn2 (same order) is bitwise equal -> self dist exactly 0.
__global__ __launch_bounds__(256) void xx_kernel(
    const float* __restrict__ x, long bstride, int C,
    double* __restrict__ xx)
{
  int i = blockIdx.x * 256 + threadIdx.x;       // BB*NPTS
  int b = i >> 10, m = i & (NPTS - 1);
  const float* xb = x + (long)b * bstride;
  double s = 0.0;
  for (int c = 0; c < C; ++c) {
    double v = (double)xb[(long)c * NPTS + m];
    s = fma(v, v, s);
  }
  xx[i] = s;
}

// 20 rounds: local argmax over 16 regs -> 64-lane butterfly (dist,idx) with
// lowest-index tie-break -> winner lane invalidates. No __syncthreads.
__device__ __forceinline__ void select20(double (&d)[16], int lane, int* orow)
{
  int keep = 0;
  for (int s = 0; s < KK; ++s) {
    double bd = d[0]; int bj = 0;
    #pragma unroll
    for (int j = 1; j < 16; ++j)
      if (d[j] > bd) { bd = d[j]; bj = j; }     // strict > keeps lowest j (lowest m)
    int bi = bj * 64 + lane;
    #pragma unroll
    for (int o = 1; o < 64; o <<= 1) {
      double od = __shfl_xor(bd, o, 64);
      int    oi = __shfl_xor(bi, o, 64);
      if (od > bd || (od == bd && oi < bi)) { bd = od; bi = oi; }
    }
    if (lane == s) keep = bi;
    if ((bi & 63) == lane) {
      int jw = bi >> 6;
      #pragma unroll
      for (int j = 0; j < 16; ++j)
        if (j == jw) d[j] = -INFINITY;
    }
  }
  if (lane < KK) orow[lane] = keep;
}

// Block = 256 thr = 4 waves = 8 points (2 per wave). Candidate m = 64*j+lane.
template <int C, int CH>
__global__ __launch_bounds__(256) void knn2_kernel(
    const float* __restrict__ x, long bstride,
    const double* __restrict__ xx,
    int* __restrict__ idx_out)
{
  const int t = threadIdx.x, w = t >> 6, lane = t & 63;
  const int b = blockIdx.y;
  const int n0 = blockIdx.x * 8;
  const int pa = n0 + 2 * w, pb = pa + 1;
  __shared__ float  xs[CH][NPTS];
  __shared__ double xxs[NPTS];
  const float* xb = x + (long)b * bstride;

  for (int i = t; i < NPTS; i += 256) xxs[i] = xx[(long)b * NPTS + i];

  double dotA[16], dotB[16];
  #pragma unroll
  for (int j = 0; j < 16; ++j) { dotA[j] = 0.0; dotB[j] = 0.0; }

  for (int c0 = 0; c0 < C; c0 += CH) {
    __syncthreads();
    for (int i = t; i < CH * NPTS; i += 256)
      (&xs[0][0])[i] = xb[(long)(c0 + (i >> 10)) * NPTS + (i & (NPTS - 1))];
    __syncthreads();
    #pragma unroll
    for (int cc = 0; cc < CH; ++cc) {
      double ca = (double)xs[cc][pa];           // broadcast reads
      double cb = (double)xs[cc][pb];
      #pragma unroll
      for (int j = 0; j < 16; ++j) {
        double v = (double)xs[cc][j * 64 + lane];
        dotA[j] = fma(ca, v, dotA[j]);
        dotB[j] = fma(cb, v, dotB[j]);
      }
    }
  }

  double xxA = xxs[pa], xxB = xxs[pb];
  double dA[16], dB[16];
  #pragma unroll
  for (int j = 0; j < 16; ++j) {
    double xm = xxs[j * 64 + lane];
    dA[j] = (2.0 * dotA[j] - xxA) - xm;         // m==pa: (2X-X)-X == 0 exactly
    dB[j] = (2.0 * dotB[j] - xxB) - xm;
  }
  select20(dA, lane, idx_out + ((long)b * NPTS + pa) * KK);
  select20(dB, lane, idx_out + ((long)b * NPTS + pb) * KK);
}

// ==================== Fused EdgeConv (single pass) ======================
// y[o][n][k] = sum_c w1[o][c]*x[c][j_k] + sum_c (w2-w1)[o][c]*x[c][n]
// One pass computes raw max over k (norm+lrelu monotone since gamma>0) and
// sum/sumsq over k for BN stats. Wave = one point; lane owns RO channels.
template <typename AccT, int C, int O, int RO, int CB>
__global__ __launch_bounds__(256) void ec_fused(
    const float* __restrict__ x, long bstride,
    const int* __restrict__ idx,
    const float* __restrict__ W,
    double* __restrict__ sums,
    AccT* __restrict__ yraw)          // [b][n][O] raw max over k
{
  const int t = threadIdx.x, b = blockIdx.y;
  const int p = t >> 6, lane = t & 63;
  const int n0 = blockIdx.x * 4;
  const int n = n0 + p;
  const int obase = lane * RO;
  const int OP = O + 4, CBP = CB + 1;
  const float* xb = x + (long)b * bstride;

  extern __shared__ char smraw[];
  float* s_w1  = (float*)smraw;               // [CB][OP]
  float* s_wd  = s_w1 + CB * OP;              // [CB][OP]  (w2 - w1)
  float* s_xg  = s_wd + CB * OP;              // [4][KK][CBP] gathered nbr x
  float* s_ctr = s_xg + 4 * KK * CBP;         // [4][CB]
  int*   s_jj  = (int*)(s_ctr + 4 * CB);      // [4][KK]
  AccT*  red   = (AccT*)smraw;                // epilogue alias: [2][4][O]

  if (t < 4 * KK) {
    int pp = t / KK, k = t - pp * KK;
    s_jj[t] = idx[((long)b * NPTS + (n0 + pp)) * KK + k];
  }

  AccT kacc[RO][KK];
  AccT cacc[RO];
  #pragma unroll
  for (int r = 0; r < RO; ++r) {
    cacc[r] = (AccT)0;
    #pragma unroll
    for (int k = 0; k < KK; ++k) kacc[r][k] = (AccT)0;
  }

  for (int c0 = 0; c0 < C; c0 += CB) {
    __syncthreads();
    for (int i = t; i < CB * O; i += 256) {
      int o = i / CB, cc = i - o * CB;
      float a  = W[(long)o * (2 * C) + c0 + cc];
      float b2 = W[(long)o * (2 * C) + C + c0 + cc];
      s_w1[cc * OP + o] = a;
      s_wd[cc * OP + o] = b2 - a;
    }
    for (int i = t; i < 4 * CB; i += 256) {
      int pp = i / CB, cc = i - pp * CB;
      s_ctr[pp * CB + cc] = xb[(long)(c0 + cc) * NPTS + n0 + pp];
    }
    for (int i = t; i < 4 * KK * CB; i += 256) {
      int k = i % KK; int rest = i / KK;
      int cc = rest % CB; int pp = rest / CB;
      s_xg[(pp * KK + k) * CBP + cc] = xb[(long)(c0 + cc) * NPTS + s_jj[pp * KK + k]];
    }
    __syncthreads();
    for (int cc = 0; cc < CB; ++cc) {
      float wv[RO], wdv[RO];
      if constexpr (RO == 4) {
        float4 a = *(const float4*)&s_w1[cc * OP + obase];
        float4 d = *(const float4*)&s_wd[cc * OP + obase];
        wv[0]=a.x; wv[1]=a.y; wv[2]=a.z; wv[3]=a.w;
        wdv[0]=d.x; wdv[1]=d.y; wdv[2]=d.z; wdv[3]=d.w;
      } else if constexpr (RO == 2) {
        float2 a = *(const float2*)&s_w1[cc * OP + obase];
        float2 d = *(const float2*)&s_wd[cc * OP + obase];
        wv[0]=a.x; wv[1]=a.y; wdv[0]=d.x; wdv[1]=d.y;
      } else {
        wv[0] = s_w1[cc * OP + obase];
        wdv[0] = s_wd[cc * OP + obase];
      }
      float cv = s_ctr[p * CB + cc];
      #pragma unroll
      for (int r = 0; r < RO; ++r) cacc[r] += (AccT)wdv[r] * (AccT)cv;
      #pragma unroll
      for (int k = 0; k < KK; ++k) {
        float fv = s_xg[(p * KK + k) * CBP + cc];
        #pragma unroll
        for (int r = 0; r < RO; ++r) kacc[r][k] += (AccT)wv[r] * (AccT)fv;
      }
    }
  }

  AccT psum[RO], psq[RO], pmx[RO];
  #pragma unroll
  for (int r = 0; r < RO; ++r) { psum[r] = (AccT)0; psq[r] = (AccT)0; pmx[r] = (AccT)(-INFINITY); }
  #pragma unroll
  for (int k = 0; k < KK; ++k) {
    #pragma unroll
    for (int r = 0; r < RO; ++r) {
      AccT y = kacc[r][k] + cacc[r];
      psum[r] += y; psq[r] += y * y;
      pmx[r] = (y > pmx[r]) ? y : pmx[r];
    }
  }
  #pragma unroll
  for (int r = 0; r < RO; ++r)
    yraw[((long)b * NPTS + n) * O + obase + r] = pmx[r];

  __syncthreads();
  #pragma unroll
  for (int r = 0; r < RO; ++r) {
    red[p * O + obase + r] = psum[r];
    red[4 * O + p * O + obase + r] = psq[r];
  }
  __syncthreads();
  if (t < O) {
    double s = 0.0, q = 0.0;
    #pragma unroll
    for (int w = 0; w < 4; ++w) {
      s += (double)red[w * O + t];
      q += (double)red[4 * O + w * O + t];
    }
    atomicAdd(&sums[t], s);
    atomicAdd(&sums[1024 + t], q);
  }
}

// normalize + lrelu the raw k-max, write into cat layout [b][o][n]
template <typename AccT, int O, int OL>
__global__ __launch_bounds__(256) void ec_norm(
    const AccT* __restrict__ yraw, const double* __restrict__ sums,
    const float* __restrict__ gamma, const float* __restrict__ beta,
    float* __restrict__ xout)
{
  int i = blockIdx.x * 256 + threadIdx.x;
  int n = i & (NPTS - 1);
  int o = (i >> 10) & (O - 1);
  int b = i >> (10 + OL);
  const double cnt = (double)BB * NPTS * KK;
  double m = sums[o] / cnt;
  double var = sums[1024 + o] / cnt - m * m;
  double inv = 1.0 / sqrt(var + (double)EPSF);
  AccT y = yraw[((long)b * NPTS + n) * O + o];
  AccT v = (y - (AccT)m) * (AccT)inv * (AccT)gamma[o] + (AccT)beta[o];
  v = (v >= (AccT)0) ? v : (AccT)0.2 * v;
  xout[(long)b * (512L * NPTS) + (long)o * NPTS + n] = (float)v;
}

// ============== Final 512->1024 conv, fused single pass =================
__device__ inline unsigned fkey(float f) {
  unsigned u = __float_as_uint(f);
  return (u & 0x80000000u) ? ~u : (u | 0x80000000u);
}
__device__ inline float keyf(unsigned k) {
  return __uint_as_float((k & 0x80000000u) ? (k ^ 0x80000000u) : ~k);
}

__global__ __launch_bounds__(256) void fin_fused(
    const float* __restrict__ cat, const float* __restrict__ W5,
    double* __restrict__ sums, unsigned* __restrict__ mkeys)
{
  const int nt = blockIdx.x, ot = blockIdx.y, t = threadIdx.x;
  const int w = t >> 6, lane = t & 63;
  const int col0 = nt * 16;
  const int b = col0 >> 10;
  const int nb = col0 & 1023;
  const int obase = lane * 4;

  __shared__ float sm[32 * 260 + 32 * 16];
  float* s_w = sm;
  float* s_f = sm + 32 * 260;

  float acc[4][4];
  #pragma unroll
  for (int r = 0; r < 4; ++r)
    #pragma unroll
    for (int j = 0; j < 4; ++j) acc[r][j] = 0.f;

  for (int c0 = 0; c0 < 512; c0 += 32) {
    __syncthreads();
    for (int i = t; i < 32 * 256; i += 256) {
      int o = i >> 5, cc = i & 31;
      s_w[cc * 260 + o] = W5[(long)(ot * 256 + o) * 512 + c0 + cc];
    }
    for (int i = t; i < 32 * 16; i += 256) {
      int cc = i >> 4, nn = i & 15;
      s_f[cc * 16 + nn] = cat[((long)b * 512 + c0 + cc) * 1024 + nb + nn];
    }
    __syncthreads();
    #pragma unroll 8
    for (int cc = 0; cc < 32; ++cc) {
      float4 wq = *(const float4*)&s_w[cc * 260 + obase];
      float4 fq = *(const float4*)&s_f[cc * 16 + w * 4];
      float wv[4] = {wq.x, wq.y, wq.z, wq.w};
      float fv[4] = {fq.x, fq.y, fq.z, fq.w};
      #pragma unroll
      for (int r = 0; r < 4; ++r)
        #pragma unroll
        for (int j = 0; j < 4; ++j) acc[r][j] += wv[r] * fv[j];
    }
  }

  float psum[4], psq[4], pmx[4];
  #pragma unroll
  for (int r = 0; r < 4; ++r) {
    psum[r] = 0.f; psq[r] = 0.f; pmx[r] = -INFINITY;
    #pragma unroll
    for (int j = 0; j < 4; ++j) {
      float v = acc[r][j];
      psum[r] += v; psq[r] += v * v; pmx[r] = fmaxf(pmx[r], v);
    }
  }
  __syncthreads();
  float* red_s = sm;
  float* red_q = sm + 1024;
  float* red_m = sm + 2048;
  #pragma unroll
  for (int r = 0; r < 4; ++r) {
    red_s[w * 256 + obase + r] = psum[r];
    red_q[w * 256 + obase + r] = psq[r];
    red_m[w * 256 + obase + r] = pmx[r];
  }
  __syncthreads();
  if (t < 256) {
    float s = 0.f, q = 0.f, m = -INFINITY;
    #pragma unroll
    for (int ww = 0; ww < 4; ++ww) {
      s += red_s[ww * 256 + t];
      q += red_q[ww * 256 + t];
      m = fmaxf(m, red_m[ww * 256 + t]);
    }
    int o = ot * 256 + t;
    atomicAdd(&sums[o], (double)s);
    atomicAdd(&sums[1024 + o], (double)q);
    atomicMax(&mkeys[b * 1024 + o], fkey(m));
  }
}

__global__ __launch_bounds__(256) void fin_norm(
    const unsigned* __restrict__ mkeys, const double* __restrict__ sums,
    const float* __restrict__ g, const float* __restrict__ bt,
    float* __restrict__ out)
{
  int i = blockIdx.x * 256 + threadIdx.x;   // 8192
  int o = i & 1023;
  double m = sums[o] / 8192.0;
  double var = sums[1024 + o] / 8192.0 - m * m;
  float inv = (float)(1.0 / sqrt(var + (double)EPSF));
  float y = keyf(mkeys[i]);
  float v = (y - (float)m) * inv * g[o] + bt[o];
  out[i] = (v >= 0.f) ? v : 0.2f * v;
}

// ============================ launch ====================================
static size_t ec_lds_bytes(int C, int O, int CB, size_t accsz) {
  size_t stage = (size_t)CB * (O + 4) * 4 * 2 + (size_t)4 * KK * (CB + 1) * 4
               + (size_t)4 * CB * 4 + (size_t)4 * KK * 4;
  size_t red = (size_t)8 * O * accsz;
  return stage > red ? stage : red;
}

extern "C" void kernel_launch(void* const* d_in, const int* in_sizes, int n_in,
                              void* d_out, int out_size, void* d_ws, size_t ws_size,
                              hipStream_t stream)
{
  (void)in_sizes; (void)n_in; (void)out_size; (void)ws_size;
  const float* x0 = (const float*)d_in[0];
  const float* W1 = (const float*)d_in[1];
  const float* g1 = (const float*)d_in[2];
  const float* b1 = (const float*)d_in[3];
  const float* W2 = (const float*)d_in[4];
  const float* g2 = (const float*)d_in[5];
  const float* b2 = (const float*)d_in[6];
  const float* W3 = (const float*)d_in[7];
  const float* g3 = (const float*)d_in[8];
  const float* b3 = (const float*)d_in[9];
  const float* W4 = (const float*)d_in[10];
  const float* g4 = (const float*)d_in[11];
  const float* b4 = (const float*)d_in[12];
  const float* W5 = (const float*)d_in[13];
  const float* g5 = (const float*)d_in[14];
  const float* b5 = (const float*)d_in[15];
  float* outp = (float*)d_out;

  char* w = (char*)d_ws;
  double*   sums   = (double*)w;   w += 2048 * sizeof(double);                // 16 KB
  unsigned* mkeys  = (unsigned*)w; w += (size_t)BB * 1024 * sizeof(unsigned); // 32 KB
  int*      idxbuf = (int*)w;      w += (size_t)BB * NPTS * KK * sizeof(int); // 640 KB
  double*   xxbuf  = (double*)w;   w += (size_t)BB * NPTS * sizeof(double);   // 64 KB
  char*     yraw   = w;            w += (size_t)BB * NPTS * 128 * sizeof(double); // 8 MB (max)
  float*    cat    = (float*)w;    // 8 * 512 * 1024 * 4 = 16 MB

  const long catbs = 512L * NPTS;
  dim3 gknn(NPTS / 8, BB);
  dim3 gec(NPTS / 4, BB);
  const int gxx = BB * NPTS / 256;

  // ---- layer 1: x0 (C=3) -> cat[0:64), fp64 acc ----
  {
    xx_kernel<<<gxx, 256, 0, stream>>>(x0, 3L * NPTS, 3, xxbuf);
    knn2_kernel<3, 3><<<gknn, 256, 0, stream>>>(x0, 3L * NPTS, xxbuf, idxbuf);
    hipMemsetAsync(sums, 0, 2048 * sizeof(double), stream);
    ec_fused<double, 3, 64, 1, 3><<<gec, 256, ec_lds_bytes(3, 64, 3, 8), stream>>>(
        x0, 3L * NPTS, idxbuf, W1, sums, (double*)yraw);
    ec_norm<double, 64, 6><<<BB * 64 * NPTS / 256, 256, 0, stream>>>(
        (const double*)yraw, sums, g1, b1, cat);
  }
  // ---- layer 2: cat[0:64) -> cat[64:128), fp64 acc ----
  {
    xx_kernel<<<gxx, 256, 0, stream>>>(cat, catbs, 64, xxbuf);
    knn2_kernel<64, 8><<<gknn, 256, 0, stream>>>(cat, catbs, xxbuf, idxbuf);
    hipMemsetAsync(sums, 0, 2048 * sizeof(double), stream);
    ec_fused<double, 64, 64, 1, 16><<<gec, 256, ec_lds_bytes(64, 64, 16, 8), stream>>>(
        cat, catbs, idxbuf, W2, sums, (double*)yraw);
    ec_norm<double, 64, 6><<<BB * 64 * NPTS / 256, 256, 0, stream>>>(
        (const double*)yraw, sums, g2, b2, cat + 64 * NPTS);
  }
  // ---- layer 3: cat[64:128) -> cat[128:256), fp64 acc ----
  {
    xx_kernel<<<gxx, 256, 0, stream>>>(cat + 64 * NPTS, catbs, 64, xxbuf);
    knn2_kernel<64, 8><<<gknn, 256, 0, stream>>>(cat + 64 * NPTS, catbs, xxbuf, idxbuf);
    hipMemsetAsync(sums, 0, 2048 * sizeof(double), stream);
    ec_fused<double, 64, 128, 2, 16><<<gec, 256, ec_lds_bytes(64, 128, 16, 8), stream>>>(
        cat + 64 * NPTS, catbs, idxbuf, W3, sums, (double*)yraw);
    ec_norm<double, 128, 7><<<BB * 128 * NPTS / 256, 256, 0, stream>>>(
        (const double*)yraw, sums, g3, b3, cat + 128 * NPTS);
  }
  // ---- layer 4: cat[128:256) -> cat[256:512), fp32 acc (continuous path) ----
  {
    xx_kernel<<<gxx, 256, 0, stream>>>(cat + 128 * NPTS, catbs, 128, xxbuf);
    knn2_kernel<128, 8><<<gknn, 256, 0, stream>>>(cat + 128 * NPTS, catbs, xxbuf, idxbuf);
    hipMemsetAsync(sums, 0, 2048 * sizeof(double), stream);
    ec_fused<float, 128, 256, 4, 16><<<gec, 256, ec_lds_bytes(128, 256, 16, 4), stream>>>(
        cat + 128 * NPTS, catbs, idxbuf, W4, sums, (float*)yraw);
    ec_norm<float, 256, 8><<<BB * 256 * NPTS / 256, 256, 0, stream>>>(
        (const float*)yraw, sums, g4, b4, cat + 256 * NPTS);
  }

  // ---- final 512->1024 conv + BN + lrelu + max over n (single pass) ----
  hipMemsetAsync(sums, 0, 2048 * sizeof(double), stream);
  hipMemsetAsync(mkeys, 0, (size_t)BB * 1024 * sizeof(unsigned), stream);
  dim3 gf(512, 4);
  fin_fused<<<gf, 256, 0, stream>>>(cat, W5, sums, mkeys);
  fin_norm<<<BB * 1024 / 256, 256, 0, stream>>>(mkeys, sums, g5, b5, outp);
}

// Round 5
// 1254.954 us; speedup vs baseline: 3.7638x; 1.0025x over previous
//
#include <hip/hip_runtime.h>
#include <math.h>

#define KK 20
#define NPTS 1024
#define BB 8
#define EPSF 1e-5f

// ====================== KNN v2: wave-per-point ==========================
// xx[b][m] = sum_c x[c][m]^2, fp64, fma-chained in ascending c so the dot
// accumulation in knn2 (same order) is bitwise equal -> self dist exactly 0.
__global__ __launch_bounds__(256) void xx_kernel(
    const float* __restrict__ x, long bstride, int C,
    double* __restrict__ xx)
{
  int i = blockIdx.x * 256 + threadIdx.x;       // BB*NPTS
  int b = i >> 10, m = i & (NPTS - 1);
  const float* xb = x + (long)b * bstride;
  double s = 0.0;
  for (int c = 0; c < C; ++c) {
    double v = (double)xb[(long)c * NPTS + m];
    s = fma(v, v, s);
  }
  xx[i] = s;
}

// 20 rounds: local argmax over 16 regs -> 64-lane butterfly (dist,idx) with
// lowest-index tie-break -> winner lane invalidates. No __syncthreads.
__device__ __forceinline__ void select20(double (&d)[16], int lane, int* orow)
{
  int keep = 0;
  for (int s = 0; s < KK; ++s) {
    double bd = d[0]; int bj = 0;
    #pragma unroll
    for (int j = 1; j < 16; ++j)
      if (d[j] > bd) { bd = d[j]; bj = j; }     // strict > keeps lowest j (lowest m)
    int bi = bj * 64 + lane;
    #pragma unroll
    for (int o = 1; o < 64; o <<= 1) {
      double od = __shfl_xor(bd, o, 64);
      int    oi = __shfl_xor(bi, o, 64);
      if (od > bd || (od == bd && oi < bi)) { bd = od; bi = oi; }
    }
    if (lane == s) keep = bi;
    if ((bi & 63) == lane) {
      int jw = bi >> 6;
      #pragma unroll
      for (int j = 0; j < 16; ++j)
        if (j == jw) d[j] = -INFINITY;
    }
  }
  if (lane < KK) orow[lane] = keep;
}

// Block = 256 thr = 4 waves = 8 points (2 per wave). Candidate m = 64*j+lane.
template <int C, int CH>
__global__ __launch_bounds__(256) void knn2_kernel(
    const float* __restrict__ x, long bstride,
    const double* __restrict__ xx,
    int* __restrict__ idx_out)
{
  const int t = threadIdx.x, w = t >> 6, lane = t & 63;
  const int b = blockIdx.y;
  const int n0 = blockIdx.x * 8;
  const int pa = n0 + 2 * w, pb = pa + 1;
  __shared__ float  xs[CH][NPTS];
  __shared__ double xxs[NPTS];
  const float* xb = x + (long)b * bstride;

  for (int i = t; i < NPTS; i += 256) xxs[i] = xx[(long)b * NPTS + i];

  double dotA[16], dotB[16];
  #pragma unroll
  for (int j = 0; j < 16; ++j) { dotA[j] = 0.0; dotB[j] = 0.0; }

  for (int c0 = 0; c0 < C; c0 += CH) {
    __syncthreads();
    for (int i = t; i < CH * NPTS; i += 256)
      (&xs[0][0])[i] = xb[(long)(c0 + (i >> 10)) * NPTS + (i & (NPTS - 1))];
    __syncthreads();
    #pragma unroll
    for (int cc = 0; cc < CH; ++cc) {
      double ca = (double)xs[cc][pa];           // broadcast reads
      double cb = (double)xs[cc][pb];
      #pragma unroll
      for (int j = 0; j < 16; ++j) {
        double v = (double)xs[cc][j * 64 + lane];
        dotA[j] = fma(ca, v, dotA[j]);
        dotB[j] = fma(cb, v, dotB[j]);
      }
    }
  }

  double xxA = xxs[pa], xxB = xxs[pb];
  double dA[16], dB[16];
  #pragma unroll
  for (int j = 0; j < 16; ++j) {
    double xm = xxs[j * 64 + lane];
    dA[j] = (2.0 * dotA[j] - xxA) - xm;         // m==pa: (2X-X)-X == 0 exactly
    dB[j] = (2.0 * dotB[j] - xxB) - xm;
  }
  select20(dA, lane, idx_out + ((long)b * NPTS + pa) * KK);
  select20(dB, lane, idx_out + ((long)b * NPTS + pb) * KK);
}

// ==================== Fused EdgeConv (single pass) ======================
// y[o][n][k] = sum_c w1[o][c]*x[c][j_k] + sum_c (w2-w1)[o][c]*x[c][n]
// One pass computes raw max over k (norm+lrelu monotone since gamma>0) and
// sum/sumsq over k for BN stats. Wave = one point; lane owns RO channels.
// xg is staged k-contiguous (stride 24, 16B-aligned) so the inner loop reads
// 4 k's per broadcast ds_read_b128 instead of 20 scalar b32 reads (round-4
// profile: LDS issue ate ~45% of the VALU budget).
template <typename AccT, int C, int O, int RO, int CB>
__global__ __launch_bounds__(256) void ec_fused(
    const float* __restrict__ x, long bstride,
    const int* __restrict__ idx,
    const float* __restrict__ W,
    double* __restrict__ sums,
    AccT* __restrict__ yraw)          // [b][n][O] raw max over k
{
  const int t = threadIdx.x, b = blockIdx.y;
  const int p = t >> 6, lane = t & 63;
  const int n0 = blockIdx.x * 4;
  const int n = n0 + p;
  const int obase = lane * RO;
  const int OP = O + 4;
  const float* xb = x + (long)b * bstride;

  extern __shared__ char smraw[];
  float* s_w1  = (float*)smraw;               // [CB][OP]
  float* s_wd  = s_w1 + CB * OP;              // [CB][OP]  (w2 - w1)
  float* s_xg  = s_wd + CB * OP;              // [4][CB][24] gathered nbr x
  float* s_ctr = s_xg + 4 * CB * 24;          // [4][CB]
  int*   s_jj  = (int*)(s_ctr + 4 * CB);      // [4][KK]
  AccT*  red   = (AccT*)smraw;                // epilogue alias: [2][4][O]

  if (t < 4 * KK) {
    int pp = t / KK, k = t - pp * KK;
    s_jj[t] = idx[((long)b * NPTS + (n0 + pp)) * KK + k];
  }

  AccT kacc[RO][KK];
  AccT cacc[RO];
  #pragma unroll
  for (int r = 0; r < RO; ++r) {
    cacc[r] = (AccT)0;
    #pragma unroll
    for (int k = 0; k < KK; ++k) kacc[r][k] = (AccT)0;
  }

  for (int c0 = 0; c0 < C; c0 += CB) {
    __syncthreads();
    for (int i = t; i < CB * O; i += 256) {
      int o = i / CB, cc = i - o * CB;
      float a  = W[(long)o * (2 * C) + c0 + cc];
      float b2 = W[(long)o * (2 * C) + C + c0 + cc];
      s_w1[cc * OP + o] = a;
      s_wd[cc * OP + o] = b2 - a;
    }
    for (int i = t; i < 4 * CB; i += 256) {
      int pp = i / CB, cc = i - pp * CB;
      s_ctr[pp * CB + cc] = xb[(long)(c0 + cc) * NPTS + n0 + pp];
    }
    // k-contiguous gather staging: s_xg[pp][cc][k], row stride 24 floats
    for (int i = t; i < 4 * CB * KK; i += 256) {
      int k = i % KK; int pc = i / KK;
      int cc = pc % CB; int pp = pc / CB;
      s_xg[(pp * CB + cc) * 24 + k] = xb[(long)(c0 + cc) * NPTS + s_jj[pp * KK + k]];
    }
    __syncthreads();
    for (int cc = 0; cc < CB; ++cc) {
      float wv[RO], wdv[RO];
      if constexpr (RO == 4) {
        float4 a = *(const float4*)&s_w1[cc * OP + obase];
        float4 d = *(const float4*)&s_wd[cc * OP + obase];
        wv[0]=a.x; wv[1]=a.y; wv[2]=a.z; wv[3]=a.w;
        wdv[0]=d.x; wdv[1]=d.y; wdv[2]=d.z; wdv[3]=d.w;
      } else if constexpr (RO == 2) {
        float2 a = *(const float2*)&s_w1[cc * OP + obase];
        float2 d = *(const float2*)&s_wd[cc * OP + obase];
        wv[0]=a.x; wv[1]=a.y; wdv[0]=d.x; wdv[1]=d.y;
      } else {
        wv[0] = s_w1[cc * OP + obase];
        wdv[0] = s_wd[cc * OP + obase];
      }
      float cv = s_ctr[p * CB + cc];
      #pragma unroll
      for (int r = 0; r < RO; ++r) cacc[r] += (AccT)wdv[r] * (AccT)cv;
      const float* fp = s_xg + (p * CB + cc) * 24;
      #pragma unroll
      for (int k4 = 0; k4 < KK; k4 += 4) {
        float4 f4 = *(const float4*)(fp + k4);   // wave-uniform broadcast b128
        float fe[4] = {f4.x, f4.y, f4.z, f4.w};
        #pragma unroll
        for (int e = 0; e < 4; ++e) {
          #pragma unroll
          for (int r = 0; r < RO; ++r)
            kacc[r][k4 + e] += (AccT)wv[r] * (AccT)fe[e];
        }
      }
    }
  }

  AccT psum[RO], psq[RO], pmx[RO];
  #pragma unroll
  for (int r = 0; r < RO; ++r) { psum[r] = (AccT)0; psq[r] = (AccT)0; pmx[r] = (AccT)(-INFINITY); }
  #pragma unroll
  for (int k = 0; k < KK; ++k) {
    #pragma unroll
    for (int r = 0; r < RO; ++r) {
      AccT y = kacc[r][k] + cacc[r];
      psum[r] += y; psq[r] += y * y;
      pmx[r] = (y > pmx[r]) ? y : pmx[r];
    }
  }
  #pragma unroll
  for (int r = 0; r < RO; ++r)
    yraw[((long)b * NPTS + n) * O + obase + r] = pmx[r];

  __syncthreads();
  #pragma unroll
  for (int r = 0; r < RO; ++r) {
    red[p * O + obase + r] = psum[r];
    red[4 * O + p * O + obase + r] = psq[r];
  }
  __syncthreads();
  if (t < O) {
    double s = 0.0, q = 0.0;
    #pragma unroll
    for (int w = 0; w < 4; ++w) {
      s += (double)red[w * O + t];
      q += (double)red[4 * O + w * O + t];
    }
    atomicAdd(&sums[t], s);
    atomicAdd(&sums[1024 + t], q);
  }
}

// normalize + lrelu the raw k-max, write into cat layout [b][o][n]
template <typename AccT, int O, int OL>
__global__ __launch_bounds__(256) void ec_norm(
    const AccT* __restrict__ yraw, const double* __restrict__ sums,
    const float* __restrict__ gamma, const float* __restrict__ beta,
    float* __restrict__ xout)
{
  int i = blockIdx.x * 256 + threadIdx.x;
  int n = i & (NPTS - 1);
  int o = (i >> 10) & (O - 1);
  int b = i >> (10 + OL);
  const double cnt = (double)BB * NPTS * KK;
  double m = sums[o] / cnt;
  double var = sums[1024 + o] / cnt - m * m;
  double inv = 1.0 / sqrt(var + (double)EPSF);
  AccT y = yraw[((long)b * NPTS + n) * O + o];
  AccT v = (y - (AccT)m) * (AccT)inv * (AccT)gamma[o] + (AccT)beta[o];
  v = (v >= (AccT)0) ? v : (AccT)0.2 * v;
  xout[(long)b * (512L * NPTS) + (long)o * NPTS + n] = (float)v;
}

// ============== Final 512->1024 conv, fused single pass =================
// o-tile 512/block (lane owns 4 o at lane*4 and 4 at 256+lane*4 -> both
// float4 reads have conflict-free 16B lane stride), wave owns 4 n.
__device__ inline unsigned fkey(float f) {
  unsigned u = __float_as_uint(f);
  return (u & 0x80000000u) ? ~u : (u | 0x80000000u);
}
__device__ inline float keyf(unsigned k) {
  return __uint_as_float((k & 0x80000000u) ? (k ^ 0x80000000u) : ~k);
}

#define WST 524   // w row stride (floats): mult of 4 (b128 align), 524%32=12 spreads staging banks

__global__ __launch_bounds__(256) void fin_fused(
    const float* __restrict__ cat, const float* __restrict__ W5,
    double* __restrict__ sums, unsigned* __restrict__ mkeys)
{
  const int nt = blockIdx.x, ot = blockIdx.y, t = threadIdx.x;
  const int w = t >> 6, lane = t & 63;
  const int col0 = nt * 16;
  const int b = col0 >> 10;
  const int nb = col0 & 1023;

  __shared__ float sm[16 * WST + 16 * 16];   // 34.6 KB
  float* s_w = sm;                           // [cc][WST]
  float* s_f = sm + 16 * WST;                // [cc][16]

  float acc[2][4][4];
  #pragma unroll
  for (int h = 0; h < 2; ++h)
    #pragma unroll
    for (int r = 0; r < 4; ++r)
      #pragma unroll
      for (int j = 0; j < 4; ++j) acc[h][r][j] = 0.f;

  for (int c0 = 0; c0 < 512; c0 += 16) {
    __syncthreads();
    for (int i = t; i < 16 * 512; i += 256) {
      int o = i >> 4, cc = i & 15;
      s_w[cc * WST + o] = W5[(long)(ot * 512 + o) * 512 + c0 + cc];
    }
    for (int i = t; i < 16 * 16; i += 256) {
      int cc = i >> 4, nn = i & 15;
      s_f[cc * 16 + nn] = cat[((long)b * 512 + c0 + cc) * 1024 + nb + nn];
    }
    __syncthreads();
    #pragma unroll
    for (int cc = 0; cc < 16; ++cc) {
      float4 wA = *(const float4*)&s_w[cc * WST + lane * 4];
      float4 wB = *(const float4*)&s_w[cc * WST + 256 + lane * 4];
      float4 fq = *(const float4*)&s_f[cc * 16 + w * 4];
      float wa[4] = {wA.x, wA.y, wA.z, wA.w};
      float wb[4] = {wB.x, wB.y, wB.z, wB.w};
      float fv[4] = {fq.x, fq.y, fq.z, fq.w};
      #pragma unroll
      for (int r = 0; r < 4; ++r)
        #pragma unroll
        for (int j = 0; j < 4; ++j) {
          acc[0][r][j] += wa[r] * fv[j];
          acc[1][r][j] += wb[r] * fv[j];
        }
    }
  }

  float psum[2][4], psq[2][4], pmx[2][4];
  #pragma unroll
  for (int h = 0; h < 2; ++h)
    #pragma unroll
    for (int r = 0; r < 4; ++r) {
      psum[h][r] = 0.f; psq[h][r] = 0.f; pmx[h][r] = -INFINITY;
      #pragma unroll
      for (int j = 0; j < 4; ++j) {
        float v = acc[h][r][j];
        psum[h][r] += v; psq[h][r] += v * v; pmx[h][r] = fmaxf(pmx[h][r], v);
      }
    }
  __syncthreads();
  float* red_s = sm;            // [4][512]
  float* red_q = sm + 2048;     // [4][512]
  float* red_m = sm + 4096;     // [4][512]
  #pragma unroll
  for (int h = 0; h < 2; ++h)
    #pragma unroll
    for (int r = 0; r < 4; ++r) {
      int oo = h * 256 + lane * 4 + r;
      red_s[w * 512 + oo] = psum[h][r];
      red_q[w * 512 + oo] = psq[h][r];
      red_m[w * 512 + oo] = pmx[h][r];
    }
  __syncthreads();
  for (int oo = t; oo < 512; oo += 256) {
    float s = 0.f, q = 0.f, m = -INFINITY;
    #pragma unroll
    for (int ww = 0; ww < 4; ++ww) {
      s += red_s[ww * 512 + oo];
      q += red_q[ww * 512 + oo];
      m = fmaxf(m, red_m[ww * 512 + oo]);
    }
    int o = ot * 512 + oo;
    atomicAdd(&sums[o], (double)s);
    atomicAdd(&sums[1024 + o], (double)q);
    atomicMax(&mkeys[b * 1024 + o], fkey(m));
  }
}

__global__ __launch_bounds__(256) void fin_norm(
    const unsigned* __restrict__ mkeys, const double* __restrict__ sums,
    const float* __restrict__ g, const float* __restrict__ bt,
    float* __restrict__ out)
{
  int i = blockIdx.x * 256 + threadIdx.x;   // 8192
  int o = i & 1023;
  double m = sums[o] / 8192.0;
  double var = sums[1024 + o] / 8192.0 - m * m;
  float inv = (float)(1.0 / sqrt(var + (double)EPSF));
  float y = keyf(mkeys[i]);
  float v = (y - (float)m) * inv * g[o] + bt[o];
  out[i] = (v >= 0.f) ? v : 0.2f * v;
}

// ============================ launch ====================================
static size_t ec_lds_bytes(int C, int O, int CB, size_t accsz) {
  size_t stage = (size_t)CB * (O + 4) * 4 * 2 + (size_t)4 * CB * 24 * 4
               + (size_t)4 * CB * 4 + (size_t)4 * KK * 4;
  size_t red = (size_t)8 * O * accsz;
  return stage > red ? stage : red;
}

extern "C" void kernel_launch(void* const* d_in, const int* in_sizes, int n_in,
                              void* d_out, int out_size, void* d_ws, size_t ws_size,
                              hipStream_t stream)
{
  (void)in_sizes; (void)n_in; (void)out_size; (void)ws_size;
  const float* x0 = (const float*)d_in[0];
  const float* W1 = (const float*)d_in[1];
  const float* g1 = (const float*)d_in[2];
  const float* b1 = (const float*)d_in[3];
  const float* W2 = (const float*)d_in[4];
  const float* g2 = (const float*)d_in[5];
  const float* b2 = (const float*)d_in[6];
  const float* W3 = (const float*)d_in[7];
  const float* g3 = (const float*)d_in[8];
  const float* b3 = (const float*)d_in[9];
  const float* W4 = (const float*)d_in[10];
  const float* g4 = (const float*)d_in[11];
  const float* b4 = (const float*)d_in[12];
  const float* W5 = (const float*)d_in[13];
  const float* g5 = (const float*)d_in[14];
  const float* b5 = (const float*)d_in[15];
  float* outp = (float*)d_out;

  char* w = (char*)d_ws;
  double*   sums   = (double*)w;   w += 2048 * sizeof(double);                // 16 KB
  unsigned* mkeys  = (unsigned*)w; w += (size_t)BB * 1024 * sizeof(unsigned); // 32 KB
  int*      idxbuf = (int*)w;      w += (size_t)BB * NPTS * KK * sizeof(int); // 640 KB
  double*   xxbuf  = (double*)w;   w += (size_t)BB * NPTS * sizeof(double);   // 64 KB
  char*     yraw   = w;            w += (size_t)BB * NPTS * 128 * sizeof(double); // 8 MB (max)
  float*    cat    = (float*)w;    // 8 * 512 * 1024 * 4 = 16 MB

  const long catbs = 512L * NPTS;
  dim3 gknn(NPTS / 8, BB);
  dim3 gec(NPTS / 4, BB);
  const int gxx = BB * NPTS / 256;

  // ---- layer 1: x0 (C=3) -> cat[0:64), fp64 acc ----
  {
    xx_kernel<<<gxx, 256, 0, stream>>>(x0, 3L * NPTS, 3, xxbuf);
    knn2_kernel<3, 3><<<gknn, 256, 0, stream>>>(x0, 3L * NPTS, xxbuf, idxbuf);
    hipMemsetAsync(sums, 0, 2048 * sizeof(double), stream);
    ec_fused<double, 3, 64, 1, 3><<<gec, 256, ec_lds_bytes(3, 64, 3, 8), stream>>>(
        x0, 3L * NPTS, idxbuf, W1, sums, (double*)yraw);
    ec_norm<double, 64, 6><<<BB * 64 * NPTS / 256, 256, 0, stream>>>(
        (const double*)yraw, sums, g1, b1, cat);
  }
  // ---- layer 2: cat[0:64) -> cat[64:128), fp64 acc ----
  {
    xx_kernel<<<gxx, 256, 0, stream>>>(cat, catbs, 64, xxbuf);
    knn2_kernel<64, 8><<<gknn, 256, 0, stream>>>(cat, catbs, xxbuf, idxbuf);
    hipMemsetAsync(sums, 0, 2048 * sizeof(double), stream);
    ec_fused<double, 64, 64, 1, 16><<<gec, 256, ec_lds_bytes(64, 64, 16, 8), stream>>>(
        cat, catbs, idxbuf, W2, sums, (double*)yraw);
    ec_norm<double, 64, 6><<<BB * 64 * NPTS / 256, 256, 0, stream>>>(
        (const double*)yraw, sums, g2, b2, cat + 64 * NPTS);
  }
  // ---- layer 3: cat[64:128) -> cat[128:256), fp64 acc ----
  {
    xx_kernel<<<gxx, 256, 0, stream>>>(cat + 64 * NPTS, catbs, 64, xxbuf);
    knn2_kernel<64, 8><<<gknn, 256, 0, stream>>>(cat + 64 * NPTS, catbs, xxbuf, idxbuf);
    hipMemsetAsync(sums, 0, 2048 * sizeof(double), stream);
    ec_fused<double, 64, 128, 2, 16><<<gec, 256, ec_lds_bytes(64, 128, 16, 8), stream>>>(
        cat + 64 * NPTS, catbs, idxbuf, W3, sums, (double*)yraw);
    ec_norm<double, 128, 7><<<BB * 128 * NPTS / 256, 256, 0, stream>>>(
        (const double*)yraw, sums, g3, b3, cat + 128 * NPTS);
  }
  // ---- layer 4: cat[128:256) -> cat[256:512), fp32 acc (continuous path) ----
  {
    xx_kernel<<<gxx, 256, 0, stream>>>(cat + 128 * NPTS, catbs, 128, xxbuf);
    knn2_kernel<128, 8><<<gknn, 256, 0, stream>>>(cat + 128 * NPTS, catbs, xxbuf, idxbuf);
    hipMemsetAsync(sums, 0, 2048 * sizeof(double), stream);
    ec_fused<float, 128, 256, 4, 16><<<gec, 256, ec_lds_bytes(128, 256, 16, 4), stream>>>(
        cat + 128 * NPTS, catbs, idxbuf, W4, sums, (float*)yraw);
    ec_norm<float, 256, 8><<<BB * 256 * NPTS / 256, 256, 0, stream>>>(
        (const float*)yraw, sums, g4, b4, cat + 256 * NPTS);
  }

  // ---- final 512->1024 conv + BN + lrelu + max over n (single pass) ----
  hipMemsetAsync(sums, 0, 2048 * sizeof(double), stream);
  hipMemsetAsync(mkeys, 0, (size_t)BB * 1024 * sizeof(unsigned), stream);
  dim3 gf(512, 2);
  fin_fused<<<gf, 256, 0, stream>>>(cat, W5, sums, mkeys);
  fin_norm<<<BB * 1024 / 256, 256, 0, stream>>>(mkeys, sums, g5, b5, outp);
}

// Round 6
// 1147.898 us; speedup vs baseline: 4.1148x; 1.0933x over previous
//
#include <hip/hip_runtime.h>
#include <math.h>

#define KK 20
#define NPTS 1024
#define BB 8
#define EPSF 1e-5f

// ====================== KNN: wave-per-point =============================
// xxs computed in-block from the staged chunks, fp64 fma ascending c ->
// bitwise equal to the dot chain, so self distance is exactly 0.
// 20 rounds: local argmax over 16 regs -> 64-lane butterfly (dist,idx) with
// lowest-index tie-break -> winner lane invalidates. No __syncthreads.
__device__ __forceinline__ void select20(double (&d)[16], int lane, int* orow)
{
  int keep = 0;
  for (int s = 0; s < KK; ++s) {
    double bd = d[0]; int bj = 0;
    #pragma unroll
    for (int j = 1; j < 16; ++j)
      if (d[j] > bd) { bd = d[j]; bj = j; }     // strict > keeps lowest j (lowest m)
    int bi = bj * 64 + lane;
    #pragma unroll
    for (int o = 1; o < 64; o <<= 1) {
      double od = __shfl_xor(bd, o, 64);
      int    oi = __shfl_xor(bi, o, 64);
      if (od > bd || (od == bd && oi < bi)) { bd = od; bi = oi; }
    }
    if (lane == s) keep = bi;
    if ((bi & 63) == lane) {
      int jw = bi >> 6;
      #pragma unroll
      for (int j = 0; j < 16; ++j)
        if (j == jw) d[j] = -INFINITY;
    }
  }
  if (lane < KK) orow[lane] = keep;
}

// Block = 256 thr = 4 waves = 8 points (2 per wave). Candidate m = 64*j+lane.
template <int C, int CH>
__global__ __launch_bounds__(256) void knn2_kernel(
    const float* __restrict__ x, long bstride,
    int* __restrict__ idx_out)
{
  const int t = threadIdx.x, w = t >> 6, lane = t & 63;
  const int b = blockIdx.y;
  const int n0 = blockIdx.x * 8;
  const int pa = n0 + 2 * w, pb = pa + 1;
  __shared__ float  xs[CH][NPTS];
  __shared__ double xxs[NPTS];
  const float* xb = x + (long)b * bstride;

  for (int i = t; i < NPTS; i += 256) xxs[i] = 0.0;

  double dotA[16], dotB[16];
  #pragma unroll
  for (int j = 0; j < 16; ++j) { dotA[j] = 0.0; dotB[j] = 0.0; }

  for (int c0 = 0; c0 < C; c0 += CH) {
    __syncthreads();
    for (int i = t; i < CH * NPTS; i += 256)
      (&xs[0][0])[i] = xb[(long)(c0 + (i >> 10)) * NPTS + (i & (NPTS - 1))];
    __syncthreads();
    // xx accumulation: thread owns m = t + 256q; ascending c order.
    for (int m = t; m < NPTS; m += 256) {
      double s = xxs[m];
      #pragma unroll
      for (int cc = 0; cc < CH; ++cc) {
        double v = (double)xs[cc][m];
        s = fma(v, v, s);
      }
      xxs[m] = s;
    }
    #pragma unroll
    for (int cc = 0; cc < CH; ++cc) {
      double ca = (double)xs[cc][pa];           // broadcast reads
      double cb = (double)xs[cc][pb];
      #pragma unroll
      for (int j = 0; j < 16; ++j) {
        double v = (double)xs[cc][j * 64 + lane];
        dotA[j] = fma(ca, v, dotA[j]);
        dotB[j] = fma(cb, v, dotB[j]);
      }
    }
  }
  __syncthreads();   // xxs written by other threads

  double xxA = xxs[pa], xxB = xxs[pb];
  double dA[16], dB[16];
  #pragma unroll
  for (int j = 0; j < 16; ++j) {
    double xm = xxs[j * 64 + lane];
    dA[j] = (2.0 * dotA[j] - xxA) - xm;         // m==pa: (2X-X)-X == 0 exactly
    dB[j] = (2.0 * dotB[j] - xxB) - xm;
  }
  select20(dA, lane, idx_out + ((long)b * NPTS + pa) * KK);
  select20(dB, lane, idx_out + ((long)b * NPTS + pb) * KK);
}

// ==================== Fused EdgeConv (single pass) ======================
// y[o][n][k] = sum_c w1[o][c]*x[c][j_k] + sum_c (w2-w1)[o][c]*x[c][n]
// One pass computes raw max over k (norm+lrelu monotone since gamma>0) and
// sum/sumsq over k for BN stats. Wave = one point; lane owns RO channels.
// xg staged k-contiguous (stride 24) -> 5 broadcast b128 reads per cc.
template <typename AccT, int C, int O, int RO, int CB>
__global__ __launch_bounds__(256) void ec_fused(
    const float* __restrict__ x, long bstride,
    const int* __restrict__ idx,
    const float* __restrict__ W,
    double* __restrict__ sums,
    AccT* __restrict__ yraw)          // [b][n][O] raw max over k
{
  const int t = threadIdx.x, b = blockIdx.y;
  const int p = t >> 6, lane = t & 63;
  const int n0 = blockIdx.x * 4;
  const int n = n0 + p;
  const int obase = lane * RO;
  const int OP = O + 4;
  const float* xb = x + (long)b * bstride;

  extern __shared__ char smraw[];
  float* s_w1  = (float*)smraw;               // [CB][OP]
  float* s_wd  = s_w1 + CB * OP;              // [CB][OP]  (w2 - w1)
  float* s_xg  = s_wd + CB * OP;              // [4][CB][24] gathered nbr x
  float* s_ctr = s_xg + 4 * CB * 24;          // [4][CB]
  int*   s_jj  = (int*)(s_ctr + 4 * CB);      // [4][KK]
  AccT*  red   = (AccT*)smraw;                // epilogue alias: [2][4][O]

  if (t < 4 * KK) {
    int pp = t / KK, k = t - pp * KK;
    s_jj[t] = idx[((long)b * NPTS + (n0 + pp)) * KK + k];
  }

  AccT kacc[RO][KK];
  AccT cacc[RO];
  #pragma unroll
  for (int r = 0; r < RO; ++r) {
    cacc[r] = (AccT)0;
    #pragma unroll
    for (int k = 0; k < KK; ++k) kacc[r][k] = (AccT)0;
  }

  for (int c0 = 0; c0 < C; c0 += CB) {
    __syncthreads();
    for (int i = t; i < CB * O; i += 256) {
      int o = i / CB, cc = i - o * CB;
      float a  = W[(long)o * (2 * C) + c0 + cc];
      float b2 = W[(long)o * (2 * C) + C + c0 + cc];
      s_w1[cc * OP + o] = a;
      s_wd[cc * OP + o] = b2 - a;
    }
    for (int i = t; i < 4 * CB; i += 256) {
      int pp = i / CB, cc = i - pp * CB;
      s_ctr[pp * CB + cc] = xb[(long)(c0 + cc) * NPTS + n0 + pp];
    }
    for (int i = t; i < 4 * CB * KK; i += 256) {
      int k = i % KK; int pc = i / KK;
      int cc = pc % CB; int pp = pc / CB;
      s_xg[(pp * CB + cc) * 24 + k] = xb[(long)(c0 + cc) * NPTS + s_jj[pp * KK + k]];
    }
    __syncthreads();
    for (int cc = 0; cc < CB; ++cc) {
      float wv[RO], wdv[RO];
      if constexpr (RO == 4) {
        float4 a = *(const float4*)&s_w1[cc * OP + obase];
        float4 d = *(const float4*)&s_wd[cc * OP + obase];
        wv[0]=a.x; wv[1]=a.y; wv[2]=a.z; wv[3]=a.w;
        wdv[0]=d.x; wdv[1]=d.y; wdv[2]=d.z; wdv[3]=d.w;
      } else if constexpr (RO == 2) {
        float2 a = *(const float2*)&s_w1[cc * OP + obase];
        float2 d = *(const float2*)&s_wd[cc * OP + obase];
        wv[0]=a.x; wv[1]=a.y; wdv[0]=d.x; wdv[1]=d.y;
      } else {
        wv[0] = s_w1[cc * OP + obase];
        wdv[0] = s_wd[cc * OP + obase];
      }
      float cv = s_ctr[p * CB + cc];
      #pragma unroll
      for (int r = 0; r < RO; ++r) cacc[r] += (AccT)wdv[r] * (AccT)cv;
      const float* fp = s_xg + (p * CB + cc) * 24;
      #pragma unroll
      for (int k4 = 0; k4 < KK; k4 += 4) {
        float4 f4 = *(const float4*)(fp + k4);   // wave-uniform broadcast b128
        float fe[4] = {f4.x, f4.y, f4.z, f4.w};
        #pragma unroll
        for (int e = 0; e < 4; ++e) {
          #pragma unroll
          for (int r = 0; r < RO; ++r)
            kacc[r][k4 + e] += (AccT)wv[r] * (AccT)fe[e];
        }
      }
    }
  }

  AccT psum[RO], psq[RO], pmx[RO];
  #pragma unroll
  for (int r = 0; r < RO; ++r) { psum[r] = (AccT)0; psq[r] = (AccT)0; pmx[r] = (AccT)(-INFINITY); }
  #pragma unroll
  for (int k = 0; k < KK; ++k) {
    #pragma unroll
    for (int r = 0; r < RO; ++r) {
      AccT y = kacc[r][k] + cacc[r];
      psum[r] += y; psq[r] += y * y;
      pmx[r] = (y > pmx[r]) ? y : pmx[r];
    }
  }
  #pragma unroll
  for (int r = 0; r < RO; ++r)
    yraw[((long)b * NPTS + n) * O + obase + r] = pmx[r];

  __syncthreads();
  #pragma unroll
  for (int r = 0; r < RO; ++r) {
    red[p * O + obase + r] = psum[r];
    red[4 * O + p * O + obase + r] = psq[r];
  }
  __syncthreads();
  if (t < O) {
    double s = 0.0, q = 0.0;
    #pragma unroll
    for (int w = 0; w < 4; ++w) {
      s += (double)red[w * O + t];
      q += (double)red[4 * O + w * O + t];
    }
    atomicAdd(&sums[t], s);
    atomicAdd(&sums[1024 + t], q);
  }
}

// normalize + lrelu the raw k-max, write into cat layout [b][o][n]
template <typename AccT, int O, int OL>
__global__ __launch_bounds__(256) void ec_norm(
    const AccT* __restrict__ yraw, const double* __restrict__ sums,
    const float* __restrict__ gamma, const float* __restrict__ beta,
    float* __restrict__ xout)
{
  int i = blockIdx.x * 256 + threadIdx.x;
  int n = i & (NPTS - 1);
  int o = (i >> 10) & (O - 1);
  int b = i >> (10 + OL);
  const double cnt = (double)BB * NPTS * KK;
  double m = sums[o] / cnt;
  double var = sums[1024 + o] / cnt - m * m;
  double inv = 1.0 / sqrt(var + (double)EPSF);
  AccT y = yraw[((long)b * NPTS + n) * O + o];
  AccT v = (y - (AccT)m) * (AccT)inv * (AccT)gamma[o] + (AccT)beta[o];
  v = (v >= (AccT)0) ? v : (AccT)0.2 * v;
  xout[(long)b * (512L * NPTS) + (long)o * NPTS + n] = (float)v;
}

// ============== Final 512->1024 conv, fused single pass =================
// Block: o-tile 512, n-tile 32 (same b). Wave owns 8 n, lane owns 8 o
// (lane*4 and 256+lane*4). Per cc: 4 b128 reads feed 64 FMAs (~73% FMA
// issue vs 54% in round 5); W5 staging redundancy down 4x.
__device__ inline unsigned fkey(float f) {
  unsigned u = __float_as_uint(f);
  return (u & 0x80000000u) ? ~u : (u | 0x80000000u);
}
__device__ inline float keyf(unsigned k) {
  return __uint_as_float((k & 0x80000000u) ? (k ^ 0x80000000u) : ~k);
}

#define WST 524   // w row stride (floats): mult of 4 for b128 align; %32=12 spreads banks

__global__ __launch_bounds__(256) void fin_fused(
    const float* __restrict__ cat, const float* __restrict__ W5,
    double* __restrict__ sums, unsigned* __restrict__ mkeys)
{
  const int nt = blockIdx.x, ot = blockIdx.y, t = threadIdx.x;
  const int w = t >> 6, lane = t & 63;
  const int col0 = nt * 32;
  const int b = col0 >> 10;
  const int nb = col0 & 1023;

  __shared__ float sm[16 * WST + 16 * 32];   // 34.75 KB
  float* s_w = sm;                           // [cc][WST]
  float* s_f = sm + 16 * WST;                // [cc][32]

  float acc[2][4][8];
  #pragma unroll
  for (int h = 0; h < 2; ++h)
    #pragma unroll
    for (int r = 0; r < 4; ++r)
      #pragma unroll
      for (int j = 0; j < 8; ++j) acc[h][r][j] = 0.f;

  for (int c0 = 0; c0 < 512; c0 += 16) {
    __syncthreads();
    // W staging: float4 global reads, b32 LDS writes (transposed)
    for (int i = t; i < 16 * 512 / 4; i += 256) {
      int o = i >> 2, cq = (i & 3) * 4;
      float4 wv = *(const float4*)&W5[(long)(ot * 512 + o) * 512 + c0 + cq];
      s_w[(cq + 0) * WST + o] = wv.x;
      s_w[(cq + 1) * WST + o] = wv.y;
      s_w[(cq + 2) * WST + o] = wv.z;
      s_w[(cq + 3) * WST + o] = wv.w;
    }
    for (int i = t; i < 16 * 32; i += 256) {
      int cc = i >> 5, nn = i & 31;
      s_f[cc * 32 + nn] = cat[((long)b * 512 + c0 + cc) * 1024 + nb + nn];
    }
    __syncthreads();
    #pragma unroll
    for (int cc = 0; cc < 16; ++cc) {
      float4 wA = *(const float4*)&s_w[cc * WST + lane * 4];
      float4 wB = *(const float4*)&s_w[cc * WST + 256 + lane * 4];
      float4 f0 = *(const float4*)&s_f[cc * 32 + w * 8];
      float4 f1 = *(const float4*)&s_f[cc * 32 + w * 8 + 4];
      float wa[4] = {wA.x, wA.y, wA.z, wA.w};
      float wb[4] = {wB.x, wB.y, wB.z, wB.w};
      float fv[8] = {f0.x, f0.y, f0.z, f0.w, f1.x, f1.y, f1.z, f1.w};
      #pragma unroll
      for (int r = 0; r < 4; ++r)
        #pragma unroll
        for (int j = 0; j < 8; ++j) {
          acc[0][r][j] += wa[r] * fv[j];
          acc[1][r][j] += wb[r] * fv[j];
        }
    }
  }

  float psum[2][4], psq[2][4], pmx[2][4];
  #pragma unroll
  for (int h = 0; h < 2; ++h)
    #pragma unroll
    for (int r = 0; r < 4; ++r) {
      psum[h][r] = 0.f; psq[h][r] = 0.f; pmx[h][r] = -INFINITY;
      #pragma unroll
      for (int j = 0; j < 8; ++j) {
        float v = acc[h][r][j];
        psum[h][r] += v; psq[h][r] += v * v; pmx[h][r] = fmaxf(pmx[h][r], v);
      }
    }
  __syncthreads();
  float* red_s = sm;            // [4][512]
  float* red_q = sm + 2048;     // [4][512]
  float* red_m = sm + 4096;     // [4][512]
  #pragma unroll
  for (int h = 0; h < 2; ++h)
    #pragma unroll
    for (int r = 0; r < 4; ++r) {
      int oo = h * 256 + lane * 4 + r;
      red_s[w * 512 + oo] = psum[h][r];
      red_q[w * 512 + oo] = psq[h][r];
      red_m[w * 512 + oo] = pmx[h][r];
    }
  __syncthreads();
  for (int oo = t; oo < 512; oo += 256) {
    float s = 0.f, q = 0.f, m = -INFINITY;
    #pragma unroll
    for (int ww = 0; ww < 4; ++ww) {
      s += red_s[ww * 512 + oo];
      q += red_q[ww * 512 + oo];
      m = fmaxf(m, red_m[ww * 512 + oo]);
    }
    int o = ot * 512 + oo;
    atomicAdd(&sums[o], (double)s);
    atomicAdd(&sums[1024 + o], (double)q);
    atomicMax(&mkeys[b * 1024 + o], fkey(m));
  }
}

__global__ __launch_bounds__(256) void fin_norm(
    const unsigned* __restrict__ mkeys, const double* __restrict__ sums,
    const float* __restrict__ g, const float* __restrict__ bt,
    float* __restrict__ out)
{
  int i = blockIdx.x * 256 + threadIdx.x;   // 8192
  int o = i & 1023;
  double m = sums[o] / 8192.0;
  double var = sums[1024 + o] / 8192.0 - m * m;
  float inv = (float)(1.0 / sqrt(var + (double)EPSF));
  float y = keyf(mkeys[i]);
  float v = (y - (float)m) * inv * g[o] + bt[o];
  out[i] = (v >= 0.f) ? v : 0.2f * v;
}

// ============================ launch ====================================
static size_t ec_lds_bytes(int C, int O, int CB, size_t accsz) {
  size_t stage = (size_t)CB * (O + 4) * 4 * 2 + (size_t)4 * CB * 24 * 4
               + (size_t)4 * CB * 4 + (size_t)4 * KK * 4;
  size_t red = (size_t)8 * O * accsz;
  return stage > red ? stage : red;
}

extern "C" void kernel_launch(void* const* d_in, const int* in_sizes, int n_in,
                              void* d_out, int out_size, void* d_ws, size_t ws_size,
                              hipStream_t stream)
{
  (void)in_sizes; (void)n_in; (void)out_size; (void)ws_size;
  const float* x0 = (const float*)d_in[0];
  const float* W1 = (const float*)d_in[1];
  const float* g1 = (const float*)d_in[2];
  const float* b1 = (const float*)d_in[3];
  const float* W2 = (const float*)d_in[4];
  const float* g2 = (const float*)d_in[5];
  const float* b2 = (const float*)d_in[6];
  const float* W3 = (const float*)d_in[7];
  const float* g3 = (const float*)d_in[8];
  const float* b3 = (const float*)d_in[9];
  const float* W4 = (const float*)d_in[10];
  const float* g4 = (const float*)d_in[11];
  const float* b4 = (const float*)d_in[12];
  const float* W5 = (const float*)d_in[13];
  const float* g5 = (const float*)d_in[14];
  const float* b5 = (const float*)d_in[15];
  float* outp = (float*)d_out;

  char* w = (char*)d_ws;
  double*   sums   = (double*)w;   w += 5 * 2048 * sizeof(double);            // 80 KB (5 regions)
  unsigned* mkeys  = (unsigned*)w; w += (size_t)BB * 1024 * sizeof(unsigned); // 32 KB
  int*      idxbuf = (int*)w;      w += (size_t)BB * NPTS * KK * sizeof(int); // 640 KB
  char*     yraw   = w;            w += (size_t)BB * NPTS * 128 * sizeof(double); // 8 MB (max)
  float*    cat    = (float*)w;    // 8 * 512 * 1024 * 4 = 16 MB

  double* sumsL[5] = {sums, sums + 2048, sums + 4096, sums + 6144, sums + 8192};

  const long catbs = 512L * NPTS;
  dim3 gknn(NPTS / 8, BB);
  dim3 gec(NPTS / 4, BB);

  // one memset for all stats regions + mkeys (adjacent in ws)
  hipMemsetAsync(sums, 0, 5 * 2048 * sizeof(double) + (size_t)BB * 1024 * sizeof(unsigned),
                 stream);

  // ---- layer 1: x0 (C=3) -> cat[0:64), fp64 acc ----
  knn2_kernel<3, 3><<<gknn, 256, 0, stream>>>(x0, 3L * NPTS, idxbuf);
  ec_fused<double, 3, 64, 1, 3><<<gec, 256, ec_lds_bytes(3, 64, 3, 8), stream>>>(
      x0, 3L * NPTS, idxbuf, W1, sumsL[0], (double*)yraw);
  ec_norm<double, 64, 6><<<BB * 64 * NPTS / 256, 256, 0, stream>>>(
      (const double*)yraw, sumsL[0], g1, b1, cat);

  // ---- layer 2: cat[0:64) -> cat[64:128), fp64 acc ----
  knn2_kernel<64, 8><<<gknn, 256, 0, stream>>>(cat, catbs, idxbuf);
  ec_fused<double, 64, 64, 1, 16><<<gec, 256, ec_lds_bytes(64, 64, 16, 8), stream>>>(
      cat, catbs, idxbuf, W2, sumsL[1], (double*)yraw);
  ec_norm<double, 64, 6><<<BB * 64 * NPTS / 256, 256, 0, stream>>>(
      (const double*)yraw, sumsL[1], g2, b2, cat + 64 * NPTS);

  // ---- layer 3: cat[64:128) -> cat[128:256), fp64 acc ----
  knn2_kernel<64, 8><<<gknn, 256, 0, stream>>>(cat + 64 * NPTS, catbs, idxbuf);
  ec_fused<double, 64, 128, 2, 16><<<gec, 256, ec_lds_bytes(64, 128, 16, 8), stream>>>(
      cat + 64 * NPTS, catbs, idxbuf, W3, sumsL[2], (double*)yraw);
  ec_norm<double, 128, 7><<<BB * 128 * NPTS / 256, 256, 0, stream>>>(
      (const double*)yraw, sumsL[2], g3, b3, cat + 128 * NPTS);

  // ---- layer 4: cat[128:256) -> cat[256:512), fp32 acc (continuous path) ----
  knn2_kernel<128, 8><<<gknn, 256, 0, stream>>>(cat + 128 * NPTS, catbs, idxbuf);
  ec_fused<float, 128, 256, 4, 16><<<gec, 256, ec_lds_bytes(128, 256, 16, 4), stream>>>(
      cat + 128 * NPTS, catbs, idxbuf, W4, sumsL[3], (float*)yraw);
  ec_norm<float, 256, 8><<<BB * 256 * NPTS / 256, 256, 0, stream>>>(
      (const float*)yraw, sumsL[3], g4, b4, cat + 256 * NPTS);

  // ---- final 512->1024 conv + BN + lrelu + max over n (single pass) ----
  dim3 gf(256, 2);
  fin_fused<<<gf, 256, 0, stream>>>(cat, W5, sumsL[4], mkeys);
  fin_norm<<<BB * 1024 / 256, 256, 0, stream>>>(mkeys, sumsL[4], g5, b5, outp);
}